// Round 3
// baseline (20205.800 us; speedup 1.0000x reference)
//
#include <hip/hip_runtime.h>

// LSTM encoder: V=32000 E=512 U=1024 L=2, B=64 T=256.
// Round 3: persistent cooperative scan, 256 blocks (1/CU -> co-residency
// guaranteed), hand-rolled device-scope grid barrier, checked launch with
// deterministic per-step-launch fallback. Both layers pipelined per step.

typedef _Float16 f16;
typedef _Float16 f16x8 __attribute__((ext_vector_type(8)));
typedef _Float16 f16x4 __attribute__((ext_vector_type(4)));
typedef float f32x4 __attribute__((ext_vector_type(4)));

__device__ __forceinline__ f32x4 mfma16x32(f16x8 a, f16x8 b, f32x4 c) {
  return __builtin_amdgcn_mfma_f32_16x16x32_f16(a, b, c, 0, 0, 0);
}

__device__ __forceinline__ void gl_lds16(const void* g, void* l) {
  __builtin_amdgcn_global_load_lds(
      (const __attribute__((address_space(1))) void*)g,
      (__attribute__((address_space(3))) void*)l, 16, 0, 0);
}

__device__ __forceinline__ float sigmoidf_(float x) {
  return 1.0f / (1.0f + expf(-x));
}

// ---------- transpose + cast: D[n][k] = (f16)S[k][n] ----------
__global__ __launch_bounds__(256) void k_transpose_f16(
    const float* __restrict__ S, f16* __restrict__ D, int K, int N) {
  __shared__ float tile[64][65];
  int nk = K >> 6;
  int k0 = (blockIdx.x % nk) << 6;
  int n0 = (blockIdx.x / nk) << 6;
  int tc = threadIdx.x & 63;
  int tq = threadIdx.x >> 6;
#pragma unroll
  for (int r = 0; r < 16; ++r) {
    int kk = tq * 16 + r;
    tile[kk][tc] = S[(size_t)(k0 + kk) * N + (n0 + tc)];
  }
  __syncthreads();
#pragma unroll
  for (int r = 0; r < 16; ++r) {
    int nn = tq * 16 + r;
    D[(size_t)(n0 + nn) * K + (k0 + tc)] = (f16)tile[tc][nn];
  }
}

// ---------- embedding lookup -> fp16 A0[m][512], row m = t*64 + b ----------
__global__ __launch_bounds__(256) void k_embed_f16(
    const int* __restrict__ tok, const float* __restrict__ emb,
    f16* __restrict__ A0) {
  int i = blockIdx.x * 256 + threadIdx.x;
  int m = i >> 7;
  int e = (i & 127) << 2;
  int t = m >> 6, b = m & 63;
  int tk = tok[b * 256 + t];
  const float4 v = *(const float4*)(emb + (size_t)tk * 512 + e);
  f16x4 o = {(f16)v.x, (f16)v.y, (f16)v.z, (f16)v.w};
  *(f16x4*)(A0 + (size_t)m * 512 + e) = o;
}

// ---------- C[m][n] = (f16)(sum_k A[m][k]*Bt[n][k] + bias[n]) ----------
__global__ __launch_bounds__(256) void k_gemm_f16(
    const f16* __restrict__ A, const f16* __restrict__ Bt,
    const float* __restrict__ bias, f16* __restrict__ C,
    int M, int N, int K) {
  __shared__ f16 sA[2][128 * 32];
  __shared__ f16 sB[2][128 * 32];
  const int tid = threadIdx.x, lane = tid & 63, w = tid >> 6;
  const int mb = M >> 7;
  const int bm = blockIdx.x % mb, bn = blockIdx.x / mb;
  const int am0 = bm << 7, bn0 = bn << 7;
  const int wm = w >> 1, wn = w & 1;
  const int srow = lane >> 2, sch = lane & 3;

  f32x4 acc[4][4] = {};
  const int NT = K >> 5;
  int cur = 0;

  auto stage = [&](int kt, int buf) {
#pragma unroll
    for (int q2 = 0; q2 < 2; ++q2) {
      int q = w * 2 + q2;
      int row = q * 16 + srow;
      const f16* ga = A + (size_t)(am0 + row) * K + kt * 32 + sch * 8;
      const f16* gb = Bt + (size_t)(bn0 + row) * K + kt * 32 + sch * 8;
      gl_lds16(ga, (char*)&sA[buf][0] + q * 1024);
      gl_lds16(gb, (char*)&sB[buf][0] + q * 1024);
    }
  };

  stage(0, 0);
  __syncthreads();
  for (int kt = 0; kt < NT; ++kt) {
    if (kt + 1 < NT) stage(kt + 1, cur ^ 1);
    const f16* pa = &sA[cur][(wm * 64 + (lane & 15)) * 32 + (lane >> 4) * 8];
    const f16* pb = &sB[cur][(wn * 64 + (lane & 15)) * 32 + (lane >> 4) * 8];
    f16x8 av[4], bv[4];
#pragma unroll
    for (int mf = 0; mf < 4; ++mf) av[mf] = *(const f16x8*)(pa + mf * 512);
#pragma unroll
    for (int nf = 0; nf < 4; ++nf) bv[nf] = *(const f16x8*)(pb + nf * 512);
#pragma unroll
    for (int mf = 0; mf < 4; ++mf)
#pragma unroll
      for (int nf = 0; nf < 4; ++nf)
        acc[mf][nf] = mfma16x32(av[mf], bv[nf], acc[mf][nf]);
    __syncthreads();
    cur ^= 1;
  }

#pragma unroll
  for (int mf = 0; mf < 4; ++mf)
#pragma unroll
    for (int nf = 0; nf < 4; ++nf) {
      int col = bn0 + wn * 64 + nf * 16 + (lane & 15);
      float bs = bias[col];
#pragma unroll
      for (int r = 0; r < 4; ++r) {
        int row = am0 + wm * 64 + mf * 16 + (lane >> 4) * 4 + r;
        C[(size_t)row * N + col] = (f16)(acc[mf][nf][r] + bs);
      }
    }
}

// ---------- grid barrier: monotonic counter, agent scope ----------
__device__ __forceinline__ void grid_barrier(unsigned* cnt, int step, int nb) {
  __threadfence();   // publish my block's writes at device scope
  __syncthreads();
  if (threadIdx.x == 0) {
    __hip_atomic_fetch_add(cnt, 1u, __ATOMIC_ACQ_REL, __HIP_MEMORY_SCOPE_AGENT);
    const unsigned target = (unsigned)nb * (unsigned)(step + 1);
    while (__hip_atomic_load(cnt, __ATOMIC_ACQUIRE, __HIP_MEMORY_SCOPE_AGENT) <
           target) {
      __builtin_amdgcn_s_sleep(2);
    }
  }
  __syncthreads();
  __threadfence();   // invalidate caches so fresh cross-XCD data is read
}

// ---------- one pipelined step: L0 computes h0(s), L1 computes h1(s-1) ----------
// Block owns units [4*bid, 4*bid+4) x 4 gates = 16 cols in BOTH layers.
// zred stride 17 (pad) kills the 32-way LDS bank conflict of stride 16.
__device__ __forceinline__ void step_once(
    int s, int u0, const f16x8 bvU0[8], const f16x8 bvW1[8],
    const f16x8 bvU1[8], const float bias1[4], const f16* __restrict__ XZ,
    f16* __restrict__ A1, f16* __restrict__ H1a, f16* __restrict__ H1b,
    float* __restrict__ C0, float* __restrict__ C1, float* __restrict__ out,
    float* zred) {
  const int tid = threadIdx.x, lane = tid & 63, w = tid >> 6;
  const int j = lane & 15, kg = lane >> 4;
  const int aoff = j * 1024 + w * 256 + kg * 8;
  const int erow = tid >> 2, euu = tid & 3;  // 4 consec lanes -> 4 consec units
  const int eu = u0 + euu;

  // ---- layer 0: h0(s) ----
  if (s < 256) {
    float xz[4];
    const f16* xrow = XZ + (size_t)(s * 64 + erow) * 4096;
#pragma unroll
    for (int g = 0; g < 4; ++g) xz[g] = (float)xrow[g * 1024 + eu];

    f32x4 acc[4] = {};
    if (s > 0) {
      const f16* ap = A1 + (size_t)(s - 1) * 65536 + aoff;
#pragma unroll
      for (int kt = 0; kt < 8; ++kt)
#pragma unroll
        for (int mf = 0; mf < 4; ++mf)
          acc[mf] = mfma16x32(*(const f16x8*)(ap + mf * 16384 + kt * 32),
                              bvU0[kt], acc[mf]);
    }
#pragma unroll
    for (int mf = 0; mf < 4; ++mf)
#pragma unroll
      for (int r = 0; r < 4; ++r)
        zred[w * 1088 + (mf * 16 + kg * 4 + r) * 17 + j] = acc[mf][r];
    __syncthreads();

    float z[4];
#pragma unroll
    for (int g = 0; g < 4; ++g) {
      float sm = xz[g];
#pragma unroll
      for (int wv = 0; wv < 4; ++wv)
        sm += zred[wv * 1088 + erow * 17 + g * 4 + euu];
      z[g] = sm;
    }
    float gi = sigmoidf_(z[0]), gf = sigmoidf_(z[1]);
    float gg = tanhf(z[2]), go = sigmoidf_(z[3]);
    float cn = gf * C0[erow * 1024 + eu] + gi * gg;
    C0[erow * 1024 + eu] = cn;
    A1[(size_t)(s * 64 + erow) * 1024 + eu] = (f16)(go * tanhf(cn));
  }
  __syncthreads();  // zred reuse guard between phases

  // ---- layer 1: h1(t), t = s-1 ----
  if (s >= 1) {
    const int t = s - 1;
    f32x4 acc[4] = {};
    const f16* ap = A1 + (size_t)t * 65536 + aoff;  // h0(t), synced last step
#pragma unroll
    for (int kt = 0; kt < 8; ++kt)
#pragma unroll
      for (int mf = 0; mf < 4; ++mf)
        acc[mf] = mfma16x32(*(const f16x8*)(ap + mf * 16384 + kt * 32),
                            bvW1[kt], acc[mf]);
    if (t > 0) {
      const f16* hp = ((t & 1) ? H1a : H1b) + aoff;  // h1(t-1)
#pragma unroll
      for (int kt = 0; kt < 8; ++kt)
#pragma unroll
        for (int mf = 0; mf < 4; ++mf)
          acc[mf] = mfma16x32(*(const f16x8*)(hp + mf * 16384 + kt * 32),
                              bvU1[kt], acc[mf]);
    }
#pragma unroll
    for (int mf = 0; mf < 4; ++mf)
#pragma unroll
      for (int r = 0; r < 4; ++r)
        zred[w * 1088 + (mf * 16 + kg * 4 + r) * 17 + j] = acc[mf][r];
    __syncthreads();

    float z[4];
#pragma unroll
    for (int g = 0; g < 4; ++g) {
      float sm = bias1[g];
#pragma unroll
      for (int wv = 0; wv < 4; ++wv)
        sm += zred[wv * 1088 + erow * 17 + g * 4 + euu];
      z[g] = sm;
    }
    float gi = sigmoidf_(z[0]), gf = sigmoidf_(z[1]);
    float gg = tanhf(z[2]), go = sigmoidf_(z[3]);
    float cn = gf * C1[erow * 1024 + eu] + gi * gg;
    C1[erow * 1024 + eu] = cn;
    float hn = go * tanhf(cn);
    f16* hw = (t & 1) ? H1b : H1a;
    hw[erow * 1024 + eu] = (f16)hn;
    out[(size_t)erow * 262144 + (size_t)t * 1024 + eu] = hn;
    if (t == 255) {
      out[16777216 + erow * 1024 + eu] = hn;
      out[16777216 + 65536 + erow * 1024 + eu] = cn;
    }
  }
}

#define SCAN_ARGS                                                           \
  const f16* __restrict__ XZ, const f16* __restrict__ U0t,                  \
      const f16* __restrict__ W1t, const f16* __restrict__ U1t,             \
      const float* __restrict__ b1, f16* __restrict__ A1,                   \
      f16* __restrict__ H1a, f16* __restrict__ H1b, float* __restrict__ C0, \
      float* __restrict__ C1, float* __restrict__ out

#define PRELOAD_WEIGHTS                                                 \
  const int tid_ = threadIdx.x, lane_ = tid_ & 63, w_ = tid_ >> 6;      \
  const int u0 = blockIdx.x * 4;                                       \
  const int j_ = lane_ & 15, kg_ = lane_ >> 4;                          \
  const int ncol_ = (j_ >> 2) * 1024 + u0 + (j_ & 3);                   \
  const int woff_ = ncol_ * 1024 + w_ * 256 + kg_ * 8;                  \
  f16x8 bvU0[8], bvW1[8], bvU1[8];                                      \
  _Pragma("unroll") for (int kt = 0; kt < 8; ++kt) {                    \
    bvU0[kt] = *(const f16x8*)(U0t + woff_ + kt * 32);                  \
    bvW1[kt] = *(const f16x8*)(W1t + woff_ + kt * 32);                  \
    bvU1[kt] = *(const f16x8*)(U1t + woff_ + kt * 32);                  \
  }                                                                     \
  const int eu_ = u0 + (tid_ & 3);                                      \
  float bias1[4];                                                       \
  _Pragma("unroll") for (int g = 0; g < 4; ++g) bias1[g] =              \
      b1[g * 1024 + eu_];

// persistent cooperative version: 256 blocks (1/CU), 256 grid barriers
__global__ __launch_bounds__(256, 1) void k_scan(SCAN_ARGS, unsigned* cnt) {
  __shared__ float zred[4352];
  PRELOAD_WEIGHTS
  for (int s = 0; s <= 256; ++s) {
    step_once(s, u0, bvU0, bvW1, bvU1, bias1, XZ, A1, H1a, H1b, C0, C1, out,
              zred);
    if (s < 256) grid_barrier(cnt, s, 256);
  }
}

// fallback: one step per launch (kernel boundary = barrier), identical math
__global__ __launch_bounds__(256, 1) void k_step(SCAN_ARGS, int s) {
  __shared__ float zred[4352];
  PRELOAD_WEIGHTS
  step_once(s, u0, bvU0, bvW1, bvU1, bias1, XZ, A1, H1a, H1b, C0, C1, out,
            zred);
}

extern "C" void kernel_launch(void* const* d_in, const int* in_sizes, int n_in,
                              void* d_out, int out_size, void* d_ws, size_t ws_size,
                              hipStream_t stream) {
  (void)in_sizes; (void)n_in; (void)out_size; (void)ws_size;
  const int* tokens = (const int*)d_in[0];
  const float* emb = (const float*)d_in[1];
  const float* W0 = (const float*)d_in[2];
  const float* U0 = (const float*)d_in[3];
  const float* b0 = (const float*)d_in[4];
  const float* W1 = (const float*)d_in[5];
  const float* U1 = (const float*)d_in[6];
  const float* b1 = (const float*)d_in[7];
  float* out = (float*)d_out;

  // workspace carve-up
  char* p = (char*)d_ws;
  f16* A0 = (f16*)p;   p += (size_t)16384 * 512 * 2;    // x tokens, fp16
  f16* A1 = (f16*)p;   p += (size_t)16384 * 1024 * 2;   // h0 history, fp16
  f16* W0t = (f16*)p;  p += (size_t)4096 * 512 * 2;     // W0^T
  f16* U0t = (f16*)p;  p += (size_t)4096 * 1024 * 2;    // U0^T
  f16* W1t = (f16*)p;  p += (size_t)4096 * 1024 * 2;    // W1^T
  f16* U1t = (f16*)p;  p += (size_t)4096 * 1024 * 2;    // U1^T
  f16* XZ = (f16*)p;   p += (size_t)16384 * 4096 * 2;   // xz0, rows t*64+b
  f16* H1a = (f16*)p;  p += 64 * 1024 * 2;              // h1 ping
  f16* H1b = (f16*)p;  p += 64 * 1024 * 2;              // h1 pong
  float* C0 = (float*)p; p += 64 * 1024 * 4;            // cell state L0
  float* C1 = (float*)p; p += 64 * 1024 * 4;            // cell state L1
  unsigned* cnt = (unsigned*)p; p += 256;               // barrier counter

  // weight transposes + casts
  k_transpose_f16<<<512, 256, 0, stream>>>(W0, W0t, 512, 4096);
  k_transpose_f16<<<1024, 256, 0, stream>>>(U0, U0t, 1024, 4096);
  k_transpose_f16<<<1024, 256, 0, stream>>>(W1, W1t, 1024, 4096);
  k_transpose_f16<<<1024, 256, 0, stream>>>(U1, U1t, 1024, 4096);

  // embedding
  k_embed_f16<<<8192, 256, 0, stream>>>(tokens, emb, A0);

  // layer 0 input projection: xz0 = x @ W0 + b0
  k_gemm_f16<<<4096, 256, 0, stream>>>(A0, W0t, b0, XZ, 16384, 4096, 512);

  // zero the state the scan reads
  hipMemsetAsync(C0, 0, 64 * 1024 * 4, stream);
  hipMemsetAsync(C1, 0, 64 * 1024 * 4, stream);
  hipMemsetAsync(cnt, 0, 256, stream);

  // persistent pipelined scan; checked launch + deterministic fallback
  const f16* XZc = XZ; const f16* U0c = U0t; const f16* W1c = W1t;
  const f16* U1c = U1t; const float* b1c = b1;
  f16* A1p = A1; f16* H1ap = H1a; f16* H1bp = H1b;
  float* C0p = C0; float* C1p = C1; float* outp = out; unsigned* cntp = cnt;
  void* kargs[] = {(void*)&XZc, (void*)&U0c, (void*)&W1c, (void*)&U1c,
                   (void*)&b1c, (void*)&A1p, (void*)&H1ap, (void*)&H1bp,
                   (void*)&C0p, (void*)&C1p, (void*)&outp, (void*)&cntp};
  hipError_t e = hipLaunchCooperativeKernel((const void*)k_scan, dim3(256),
                                            dim3(256), kargs, 0, stream);
  if (e != hipSuccess) {
    (void)hipGetLastError();  // clear error state; run per-step fallback
    for (int s = 0; s <= 256; ++s)
      k_step<<<256, 256, 0, stream>>>(XZ, U0t, W1t, U1t, b1, A1, H1a, H1b,
                                      C0, C1, out, s);
  }
}

// Round 4
// 19909.322 us; speedup vs baseline: 1.0149x; 1.0149x over previous
//
#include <hip/hip_runtime.h>

// LSTM encoder: V=32000 E=512 U=1024 L=2, B=64 T=256.
// Round 4: persistent cooperative scan with CONTENTION-FREE grid barrier:
// per-block arrival flags on private cache lines (release stores, no RMW),
// block-0 gather (256 parallel pollers), single broadcast release word.
// Round 3's RMW-on-one-line barrier serialized at ~307ns/RMW = 78us/step.

typedef _Float16 f16;
typedef _Float16 f16x8 __attribute__((ext_vector_type(8)));
typedef _Float16 f16x4 __attribute__((ext_vector_type(4)));
typedef float f32x4 __attribute__((ext_vector_type(4)));

__device__ __forceinline__ f32x4 mfma16x32(f16x8 a, f16x8 b, f32x4 c) {
  return __builtin_amdgcn_mfma_f32_16x16x32_f16(a, b, c, 0, 0, 0);
}

__device__ __forceinline__ void gl_lds16(const void* g, void* l) {
  __builtin_amdgcn_global_load_lds(
      (const __attribute__((address_space(1))) void*)g,
      (__attribute__((address_space(3))) void*)l, 16, 0, 0);
}

__device__ __forceinline__ float sigmoidf_(float x) {
  return 1.0f / (1.0f + expf(-x));
}

// ---------- transpose + cast: D[n][k] = (f16)S[k][n] ----------
__global__ __launch_bounds__(256) void k_transpose_f16(
    const float* __restrict__ S, f16* __restrict__ D, int K, int N) {
  __shared__ float tile[64][65];
  int nk = K >> 6;
  int k0 = (blockIdx.x % nk) << 6;
  int n0 = (blockIdx.x / nk) << 6;
  int tc = threadIdx.x & 63;
  int tq = threadIdx.x >> 6;
#pragma unroll
  for (int r = 0; r < 16; ++r) {
    int kk = tq * 16 + r;
    tile[kk][tc] = S[(size_t)(k0 + kk) * N + (n0 + tc)];
  }
  __syncthreads();
#pragma unroll
  for (int r = 0; r < 16; ++r) {
    int nn = tq * 16 + r;
    D[(size_t)(n0 + nn) * K + (k0 + tc)] = (f16)tile[tc][nn];
  }
}

// ---------- embedding lookup -> fp16 A0[m][512], row m = t*64 + b ----------
__global__ __launch_bounds__(256) void k_embed_f16(
    const int* __restrict__ tok, const float* __restrict__ emb,
    f16* __restrict__ A0) {
  int i = blockIdx.x * 256 + threadIdx.x;
  int m = i >> 7;
  int e = (i & 127) << 2;
  int t = m >> 6, b = m & 63;
  int tk = tok[b * 256 + t];
  const float4 v = *(const float4*)(emb + (size_t)tk * 512 + e);
  f16x4 o = {(f16)v.x, (f16)v.y, (f16)v.z, (f16)v.w};
  *(f16x4*)(A0 + (size_t)m * 512 + e) = o;
}

// ---------- C[m][n] = (f16)(sum_k A[m][k]*Bt[n][k] + bias[n]) ----------
__global__ __launch_bounds__(256) void k_gemm_f16(
    const f16* __restrict__ A, const f16* __restrict__ Bt,
    const float* __restrict__ bias, f16* __restrict__ C,
    int M, int N, int K) {
  __shared__ f16 sA[2][128 * 32];
  __shared__ f16 sB[2][128 * 32];
  const int tid = threadIdx.x, lane = tid & 63, w = tid >> 6;
  const int mb = M >> 7;
  const int bm = blockIdx.x % mb, bn = blockIdx.x / mb;
  const int am0 = bm << 7, bn0 = bn << 7;
  const int wm = w >> 1, wn = w & 1;
  const int srow = lane >> 2, sch = lane & 3;

  f32x4 acc[4][4] = {};
  const int NT = K >> 5;
  int cur = 0;

  auto stage = [&](int kt, int buf) {
#pragma unroll
    for (int q2 = 0; q2 < 2; ++q2) {
      int q = w * 2 + q2;
      int row = q * 16 + srow;
      const f16* ga = A + (size_t)(am0 + row) * K + kt * 32 + sch * 8;
      const f16* gb = Bt + (size_t)(bn0 + row) * K + kt * 32 + sch * 8;
      gl_lds16(ga, (char*)&sA[buf][0] + q * 1024);
      gl_lds16(gb, (char*)&sB[buf][0] + q * 1024);
    }
  };

  stage(0, 0);
  __syncthreads();
  for (int kt = 0; kt < NT; ++kt) {
    if (kt + 1 < NT) stage(kt + 1, cur ^ 1);
    const f16* pa = &sA[cur][(wm * 64 + (lane & 15)) * 32 + (lane >> 4) * 8];
    const f16* pb = &sB[cur][(wn * 64 + (lane & 15)) * 32 + (lane >> 4) * 8];
    f16x8 av[4], bv[4];
#pragma unroll
    for (int mf = 0; mf < 4; ++mf) av[mf] = *(const f16x8*)(pa + mf * 512);
#pragma unroll
    for (int nf = 0; nf < 4; ++nf) bv[nf] = *(const f16x8*)(pb + nf * 512);
#pragma unroll
    for (int mf = 0; mf < 4; ++mf)
#pragma unroll
      for (int nf = 0; nf < 4; ++nf)
        acc[mf][nf] = mfma16x32(av[mf], bv[nf], acc[mf][nf]);
    __syncthreads();
    cur ^= 1;
  }

#pragma unroll
  for (int mf = 0; mf < 4; ++mf)
#pragma unroll
    for (int nf = 0; nf < 4; ++nf) {
      int col = bn0 + wn * 64 + nf * 16 + (lane & 15);
      float bs = bias[col];
#pragma unroll
      for (int r = 0; r < 4; ++r) {
        int row = am0 + wm * 64 + mf * 16 + (lane >> 4) * 4 + r;
        C[(size_t)row * N + col] = (f16)(acc[mf][nf][r] + bs);
      }
    }
}

// ---------- contention-free grid barrier ----------
// Arrive: block b release-stores s+1 to flags[b*32] (own 128B line).
// Gather: block 0's 256 threads poll one flag each, then release-store to
// *release. Wait: one poller per block on *release. Zero atomic RMWs.
__device__ __forceinline__ void grid_barrier2(unsigned* flags,
                                              unsigned* release, int s) {
  __threadfence();  // publish this block's h-writes at device scope
  __syncthreads();
  const unsigned v = (unsigned)s + 1u;
  if (blockIdx.x == 0) {
    if (threadIdx.x == 0)
      __hip_atomic_store(&flags[0], v, __ATOMIC_RELEASE,
                         __HIP_MEMORY_SCOPE_AGENT);
    while (__hip_atomic_load(&flags[(unsigned)threadIdx.x * 32u],
                             __ATOMIC_ACQUIRE,
                             __HIP_MEMORY_SCOPE_AGENT) < v)
      __builtin_amdgcn_s_sleep(1);
    __syncthreads();
    if (threadIdx.x == 0)
      __hip_atomic_store(release, v, __ATOMIC_RELEASE,
                         __HIP_MEMORY_SCOPE_AGENT);
  } else {
    if (threadIdx.x == 0) {
      __hip_atomic_store(&flags[(unsigned)blockIdx.x * 32u], v,
                         __ATOMIC_RELEASE, __HIP_MEMORY_SCOPE_AGENT);
      while (__hip_atomic_load(release, __ATOMIC_ACQUIRE,
                               __HIP_MEMORY_SCOPE_AGENT) < v)
        __builtin_amdgcn_s_sleep(1);
    }
    __syncthreads();
  }
  __threadfence();  // discard stale cached copies before reading remote data
}

// ---------- one pipelined step: L0 computes h0(s), L1 computes h1(s-1) ----------
// Block owns units [4*bid, 4*bid+4) x 4 gates = 16 cols in BOTH layers.
// xz[4] = this step's input-projection gate values (prefetched by caller).
__device__ __forceinline__ void step_once(
    int s, int u0, const f16x8 bvU0[8], const f16x8 bvW1[8],
    const f16x8 bvU1[8], const float bias1[4], const float xz[4],
    f16* __restrict__ A1, f16* __restrict__ H1a, f16* __restrict__ H1b,
    float* __restrict__ C0, float* __restrict__ C1, float* __restrict__ out,
    float* zred) {
  const int tid = threadIdx.x, lane = tid & 63, w = tid >> 6;
  const int j = lane & 15, kg = lane >> 4;
  const int aoff = j * 1024 + w * 256 + kg * 8;
  const int erow = tid >> 2, euu = tid & 3;
  const int eu = u0 + euu;

  // ---- layer 0: h0(s) ----
  if (s < 256) {
    f32x4 acc[4] = {};
    if (s > 0) {
      const f16* ap = A1 + (size_t)(s - 1) * 65536 + aoff;
#pragma unroll
      for (int kt = 0; kt < 8; ++kt)
#pragma unroll
        for (int mf = 0; mf < 4; ++mf)
          acc[mf] = mfma16x32(*(const f16x8*)(ap + mf * 16384 + kt * 32),
                              bvU0[kt], acc[mf]);
    }
#pragma unroll
    for (int mf = 0; mf < 4; ++mf)
#pragma unroll
      for (int r = 0; r < 4; ++r)
        zred[w * 1088 + (mf * 16 + kg * 4 + r) * 17 + j] = acc[mf][r];
    __syncthreads();

    float z[4];
#pragma unroll
    for (int g = 0; g < 4; ++g) {
      float sm = xz[g];
#pragma unroll
      for (int wv = 0; wv < 4; ++wv)
        sm += zred[wv * 1088 + erow * 17 + g * 4 + euu];
      z[g] = sm;
    }
    float gi = sigmoidf_(z[0]), gf = sigmoidf_(z[1]);
    float gg = tanhf(z[2]), go = sigmoidf_(z[3]);
    float cn = gf * C0[erow * 1024 + eu] + gi * gg;
    C0[erow * 1024 + eu] = cn;
    A1[(size_t)(s * 64 + erow) * 1024 + eu] = (f16)(go * tanhf(cn));
  }
  __syncthreads();  // zred reuse guard between phases

  // ---- layer 1: h1(t), t = s-1 ----
  if (s >= 1) {
    const int t = s - 1;
    f32x4 acc[4] = {};
    const f16* ap = A1 + (size_t)t * 65536 + aoff;  // h0(t), synced last step
#pragma unroll
    for (int kt = 0; kt < 8; ++kt)
#pragma unroll
      for (int mf = 0; mf < 4; ++mf)
        acc[mf] = mfma16x32(*(const f16x8*)(ap + mf * 16384 + kt * 32),
                            bvW1[kt], acc[mf]);
    if (t > 0) {
      const f16* hp = ((t & 1) ? H1a : H1b) + aoff;  // h1(t-1)
#pragma unroll
      for (int kt = 0; kt < 8; ++kt)
#pragma unroll
        for (int mf = 0; mf < 4; ++mf)
          acc[mf] = mfma16x32(*(const f16x8*)(hp + mf * 16384 + kt * 32),
                              bvU1[kt], acc[mf]);
    }
#pragma unroll
    for (int mf = 0; mf < 4; ++mf)
#pragma unroll
      for (int r = 0; r < 4; ++r)
        zred[w * 1088 + (mf * 16 + kg * 4 + r) * 17 + j] = acc[mf][r];
    __syncthreads();

    float z[4];
#pragma unroll
    for (int g = 0; g < 4; ++g) {
      float sm = bias1[g];
#pragma unroll
      for (int wv = 0; wv < 4; ++wv)
        sm += zred[wv * 1088 + erow * 17 + g * 4 + euu];
      z[g] = sm;
    }
    float gi = sigmoidf_(z[0]), gf = sigmoidf_(z[1]);
    float gg = tanhf(z[2]), go = sigmoidf_(z[3]);
    float cn = gf * C1[erow * 1024 + eu] + gi * gg;
    C1[erow * 1024 + eu] = cn;
    float hn = go * tanhf(cn);
    f16* hw = (t & 1) ? H1b : H1a;
    hw[erow * 1024 + eu] = (f16)hn;
    out[(size_t)erow * 262144 + (size_t)t * 1024 + eu] = hn;
    if (t == 255) {
      out[16777216 + erow * 1024 + eu] = hn;
      out[16777216 + 65536 + erow * 1024 + eu] = cn;
    }
  }
}

#define SCAN_ARGS                                                           \
  const f16* __restrict__ XZ, const f16* __restrict__ U0t,                  \
      const f16* __restrict__ W1t, const f16* __restrict__ U1t,             \
      const float* __restrict__ b1, f16* __restrict__ A1,                   \
      f16* __restrict__ H1a, f16* __restrict__ H1b, float* __restrict__ C0, \
      float* __restrict__ C1, float* __restrict__ out

#define PRELOAD_WEIGHTS                                                 \
  const int tid_ = threadIdx.x, lane_ = tid_ & 63, w_ = tid_ >> 6;      \
  const int u0 = blockIdx.x * 4;                                       \
  const int j_ = lane_ & 15, kg_ = lane_ >> 4;                          \
  const int ncol_ = (j_ >> 2) * 1024 + u0 + (j_ & 3);                   \
  const int woff_ = ncol_ * 1024 + w_ * 256 + kg_ * 8;                  \
  f16x8 bvU0[8], bvW1[8], bvU1[8];                                      \
  _Pragma("unroll") for (int kt = 0; kt < 8; ++kt) {                    \
    bvU0[kt] = *(const f16x8*)(U0t + woff_ + kt * 32);                  \
    bvW1[kt] = *(const f16x8*)(W1t + woff_ + kt * 32);                  \
    bvU1[kt] = *(const f16x8*)(U1t + woff_ + kt * 32);                  \
  }                                                                     \
  const int erow_ = tid_ >> 2;                                          \
  const int eu_ = u0 + (tid_ & 3);                                      \
  float bias1[4];                                                       \
  _Pragma("unroll") for (int g = 0; g < 4; ++g) bias1[g] =              \
      b1[g * 1024 + eu_];

// persistent cooperative version: 256 blocks (1/CU), 256 grid barriers
__global__ __launch_bounds__(256, 1) void k_scan(SCAN_ARGS, unsigned* flags,
                                                 unsigned* release) {
  __shared__ float zred[4352];
  PRELOAD_WEIGHTS
  // xz gate values for step 0
  float xz[4];
#pragma unroll
  for (int g = 0; g < 4; ++g)
    xz[g] = (float)XZ[(size_t)erow_ * 4096 + g * 1024 + eu_];

  for (int s = 0; s <= 256; ++s) {
    step_once(s, u0, bvU0, bvW1, bvU1, bias1, xz, A1, H1a, H1b, C0, C1, out,
              zred);
    // prefetch next step's xz so load latency hides under the barrier spin
    float xzn[4] = {0.f, 0.f, 0.f, 0.f};
    if (s + 1 < 256) {
      const f16* xrow = XZ + (size_t)((s + 1) * 64 + erow_) * 4096;
#pragma unroll
      for (int g = 0; g < 4; ++g) xzn[g] = (float)xrow[g * 1024 + eu_];
    }
    if (s < 256) grid_barrier2(flags, release, s);
#pragma unroll
    for (int g = 0; g < 4; ++g) xz[g] = xzn[g];
  }
}

// fallback: one step per launch (kernel boundary = barrier), identical math
__global__ __launch_bounds__(256, 1) void k_step(SCAN_ARGS, int s) {
  __shared__ float zred[4352];
  PRELOAD_WEIGHTS
  float xz[4] = {0.f, 0.f, 0.f, 0.f};
  if (s < 256) {
    const f16* xrow = XZ + (size_t)(s * 64 + erow_) * 4096;
#pragma unroll
    for (int g = 0; g < 4; ++g) xz[g] = (float)xrow[g * 1024 + eu_];
  }
  step_once(s, u0, bvU0, bvW1, bvU1, bias1, xz, A1, H1a, H1b, C0, C1, out,
            zred);
}

extern "C" void kernel_launch(void* const* d_in, const int* in_sizes, int n_in,
                              void* d_out, int out_size, void* d_ws, size_t ws_size,
                              hipStream_t stream) {
  (void)in_sizes; (void)n_in; (void)out_size; (void)ws_size;
  const int* tokens = (const int*)d_in[0];
  const float* emb = (const float*)d_in[1];
  const float* W0 = (const float*)d_in[2];
  const float* U0 = (const float*)d_in[3];
  const float* b0 = (const float*)d_in[4];
  const float* W1 = (const float*)d_in[5];
  const float* U1 = (const float*)d_in[6];
  const float* b1 = (const float*)d_in[7];
  float* out = (float*)d_out;

  // workspace carve-up
  char* p = (char*)d_ws;
  f16* A0 = (f16*)p;   p += (size_t)16384 * 512 * 2;    // x tokens, fp16
  f16* A1 = (f16*)p;   p += (size_t)16384 * 1024 * 2;   // h0 history, fp16
  f16* W0t = (f16*)p;  p += (size_t)4096 * 512 * 2;     // W0^T
  f16* U0t = (f16*)p;  p += (size_t)4096 * 1024 * 2;    // U0^T
  f16* W1t = (f16*)p;  p += (size_t)4096 * 1024 * 2;    // W1^T
  f16* U1t = (f16*)p;  p += (size_t)4096 * 1024 * 2;    // U1^T
  f16* XZ = (f16*)p;   p += (size_t)16384 * 4096 * 2;   // xz0, rows t*64+b
  f16* H1a = (f16*)p;  p += 64 * 1024 * 2;              // h1 ping
  f16* H1b = (f16*)p;  p += 64 * 1024 * 2;              // h1 pong
  float* C0 = (float*)p; p += 64 * 1024 * 4;            // cell state L0
  float* C1 = (float*)p; p += 64 * 1024 * 4;            // cell state L1
  unsigned* flags = (unsigned*)p; p += 256 * 32 * 4;    // arrival flags
  unsigned* release = (unsigned*)p; p += 128;           // release word

  // weight transposes + casts
  k_transpose_f16<<<512, 256, 0, stream>>>(W0, W0t, 512, 4096);
  k_transpose_f16<<<1024, 256, 0, stream>>>(U0, U0t, 1024, 4096);
  k_transpose_f16<<<1024, 256, 0, stream>>>(W1, W1t, 1024, 4096);
  k_transpose_f16<<<1024, 256, 0, stream>>>(U1, U1t, 1024, 4096);

  // embedding
  k_embed_f16<<<8192, 256, 0, stream>>>(tokens, emb, A0);

  // layer 0 input projection: xz0 = x @ W0 + b0
  k_gemm_f16<<<4096, 256, 0, stream>>>(A0, W0t, b0, XZ, 16384, 4096, 512);

  // zero the state the scan reads
  hipMemsetAsync(C0, 0, 64 * 1024 * 4, stream);
  hipMemsetAsync(C1, 0, 64 * 1024 * 4, stream);
  hipMemsetAsync(flags, 0, 256 * 32 * 4 + 128, stream);

  // persistent pipelined scan; checked launch + deterministic fallback
  const f16* XZc = XZ; const f16* U0c = U0t; const f16* W1c = W1t;
  const f16* U1c = U1t; const float* b1c = b1;
  f16* A1p = A1; f16* H1ap = H1a; f16* H1bp = H1b;
  float* C0p = C0; float* C1p = C1; float* outp = out;
  unsigned* fl = flags; unsigned* rl = release;
  void* kargs[] = {(void*)&XZc, (void*)&U0c, (void*)&W1c, (void*)&U1c,
                   (void*)&b1c, (void*)&A1p, (void*)&H1ap, (void*)&H1bp,
                   (void*)&C0p, (void*)&C1p, (void*)&outp, (void*)&fl,
                   (void*)&rl};
  hipError_t e = hipLaunchCooperativeKernel((const void*)k_scan, dim3(256),
                                            dim3(256), kargs, 0, stream);
  if (e != hipSuccess) {
    (void)hipGetLastError();  // clear error state; run per-step fallback
    for (int s = 0; s <= 256; ++s)
      k_step<<<256, 256, 0, stream>>>(XZ, U0t, W1t, U1t, b1, A1, H1a, H1b,
                                      C0, C1, out, s);
  }
}

// Round 5
// 12993.098 us; speedup vs baseline: 1.5551x; 1.5323x over previous
//
#include <hip/hip_runtime.h>

// LSTM encoder: V=32000 E=512 U=1024 L=2, B=64 T=256.
// Round 5: persistent cooperative scan. Grid barrier with STRICT 1-writer/
// 1-reader cache lines (per-block arrive line, per-block release line) and
// RELAXED polls (no per-poll invalidate). Rounds 3+4 both burned 78us/step
// with N pollers fanning into one line (~0.3us per same-line access x 256).
// Cell state lives in registers (no global C traffic in the coop path).

typedef _Float16 f16;
typedef _Float16 f16x8 __attribute__((ext_vector_type(8)));
typedef _Float16 f16x4 __attribute__((ext_vector_type(4)));
typedef float f32x4 __attribute__((ext_vector_type(4)));

__device__ __forceinline__ f32x4 mfma16x32(f16x8 a, f16x8 b, f32x4 c) {
  return __builtin_amdgcn_mfma_f32_16x16x32_f16(a, b, c, 0, 0, 0);
}

__device__ __forceinline__ void gl_lds16(const void* g, void* l) {
  __builtin_amdgcn_global_load_lds(
      (const __attribute__((address_space(1))) void*)g,
      (__attribute__((address_space(3))) void*)l, 16, 0, 0);
}

__device__ __forceinline__ float sigmoidf_(float x) {
  return 1.0f / (1.0f + expf(-x));
}

// ---------- transpose + cast: D[n][k] = (f16)S[k][n] ----------
__global__ __launch_bounds__(256) void k_transpose_f16(
    const float* __restrict__ S, f16* __restrict__ D, int K, int N) {
  __shared__ float tile[64][65];
  int nk = K >> 6;
  int k0 = (blockIdx.x % nk) << 6;
  int n0 = (blockIdx.x / nk) << 6;
  int tc = threadIdx.x & 63;
  int tq = threadIdx.x >> 6;
#pragma unroll
  for (int r = 0; r < 16; ++r) {
    int kk = tq * 16 + r;
    tile[kk][tc] = S[(size_t)(k0 + kk) * N + (n0 + tc)];
  }
  __syncthreads();
#pragma unroll
  for (int r = 0; r < 16; ++r) {
    int nn = tq * 16 + r;
    D[(size_t)(n0 + nn) * K + (k0 + tc)] = (f16)tile[tc][nn];
  }
}

// ---------- embedding lookup -> fp16 A0[m][512], row m = t*64 + b ----------
__global__ __launch_bounds__(256) void k_embed_f16(
    const int* __restrict__ tok, const float* __restrict__ emb,
    f16* __restrict__ A0) {
  int i = blockIdx.x * 256 + threadIdx.x;
  int m = i >> 7;
  int e = (i & 127) << 2;
  int t = m >> 6, b = m & 63;
  int tk = tok[b * 256 + t];
  const float4 v = *(const float4*)(emb + (size_t)tk * 512 + e);
  f16x4 o = {(f16)v.x, (f16)v.y, (f16)v.z, (f16)v.w};
  *(f16x4*)(A0 + (size_t)m * 512 + e) = o;
}

// ---------- C[m][n] = (f16)(sum_k A[m][k]*Bt[n][k] + bias[n]) ----------
__global__ __launch_bounds__(256) void k_gemm_f16(
    const f16* __restrict__ A, const f16* __restrict__ Bt,
    const float* __restrict__ bias, f16* __restrict__ C,
    int M, int N, int K) {
  __shared__ f16 sA[2][128 * 32];
  __shared__ f16 sB[2][128 * 32];
  const int tid = threadIdx.x, lane = tid & 63, w = tid >> 6;
  const int mb = M >> 7;
  const int bm = blockIdx.x % mb, bn = blockIdx.x / mb;
  const int am0 = bm << 7, bn0 = bn << 7;
  const int wm = w >> 1, wn = w & 1;
  const int srow = lane >> 2, sch = lane & 3;

  f32x4 acc[4][4] = {};
  const int NT = K >> 5;
  int cur = 0;

  auto stage = [&](int kt, int buf) {
#pragma unroll
    for (int q2 = 0; q2 < 2; ++q2) {
      int q = w * 2 + q2;
      int row = q * 16 + srow;
      const f16* ga = A + (size_t)(am0 + row) * K + kt * 32 + sch * 8;
      const f16* gb = Bt + (size_t)(bn0 + row) * K + kt * 32 + sch * 8;
      gl_lds16(ga, (char*)&sA[buf][0] + q * 1024);
      gl_lds16(gb, (char*)&sB[buf][0] + q * 1024);
    }
  };

  stage(0, 0);
  __syncthreads();
  for (int kt = 0; kt < NT; ++kt) {
    if (kt + 1 < NT) stage(kt + 1, cur ^ 1);
    const f16* pa = &sA[cur][(wm * 64 + (lane & 15)) * 32 + (lane >> 4) * 8];
    const f16* pb = &sB[cur][(wn * 64 + (lane & 15)) * 32 + (lane >> 4) * 8];
    f16x8 av[4], bv[4];
#pragma unroll
    for (int mf = 0; mf < 4; ++mf) av[mf] = *(const f16x8*)(pa + mf * 512);
#pragma unroll
    for (int nf = 0; nf < 4; ++nf) bv[nf] = *(const f16x8*)(pb + nf * 512);
#pragma unroll
    for (int mf = 0; mf < 4; ++mf)
#pragma unroll
      for (int nf = 0; nf < 4; ++nf)
        acc[mf][nf] = mfma16x32(av[mf], bv[nf], acc[mf][nf]);
    __syncthreads();
    cur ^= 1;
  }

#pragma unroll
  for (int mf = 0; mf < 4; ++mf)
#pragma unroll
    for (int nf = 0; nf < 4; ++nf) {
      int col = bn0 + wn * 64 + nf * 16 + (lane & 15);
      float bs = bias[col];
#pragma unroll
      for (int r = 0; r < 4; ++r) {
        int row = am0 + wm * 64 + mf * 16 + (lane >> 4) * 4 + r;
        C[(size_t)row * N + col] = (f16)(acc[mf][nf][r] + bs);
      }
    }
}

// ---------- grid barrier: every line has exactly 1 writer + 1 poller ----------
// arr[b*32]: written by block b (thread 0), polled by block 0 (thread b).
// rel[b*32]: written by block 0 (thread b), polled by block b (thread 0).
// Polls RELAXED (no per-poll cache invalidate); one threadfence pair per step
// provides publish (pre) and invalidate (post) exactly once.
__device__ __forceinline__ void grid_barrier3(unsigned* arr, unsigned* rel,
                                              int s) {
  __threadfence();  // publish this block's h-writes (wb to coherence point)
  __syncthreads();
  const unsigned v = (unsigned)s + 1u;
  const int bid = blockIdx.x, tid = threadIdx.x;
  if (bid == 0) {
    if (tid > 0) {
      while (__hip_atomic_load(&arr[(unsigned)tid * 32u], __ATOMIC_RELAXED,
                               __HIP_MEMORY_SCOPE_AGENT) < v)
        __builtin_amdgcn_s_sleep(1);
    }
    __syncthreads();  // all arrivals observed (loads consumed by loop exit)
    if (tid > 0)
      __hip_atomic_store(&rel[(unsigned)tid * 32u], v, __ATOMIC_RELAXED,
                         __HIP_MEMORY_SCOPE_AGENT);
  } else {
    if (tid == 0) {
      __hip_atomic_store(&arr[(unsigned)bid * 32u], v, __ATOMIC_RELAXED,
                         __HIP_MEMORY_SCOPE_AGENT);
      while (__hip_atomic_load(&rel[(unsigned)bid * 32u], __ATOMIC_RELAXED,
                               __HIP_MEMORY_SCOPE_AGENT) < v)
        __builtin_amdgcn_s_sleep(1);
    }
    __syncthreads();
  }
  __threadfence();  // drop stale cached lines before reading remote h
}

// ---------- one pipelined step: L0 computes h0(s), L1 computes h1(s-1) ----------
// Block owns units [4*bid, 4*bid+4) x 4 gates = 16 cols in BOTH layers.
// c0/c1 = per-thread register cell state for this thread's (row,unit).
__device__ __forceinline__ void step_once(
    int s, int u0, const f16x8 bvU0[8], const f16x8 bvW1[8],
    const f16x8 bvU1[8], const float bias1[4], const float xz[4],
    f16* __restrict__ A1, f16* __restrict__ H1a, f16* __restrict__ H1b,
    float& c0, float& c1, float* __restrict__ out, float* zred) {
  const int tid = threadIdx.x, lane = tid & 63, w = tid >> 6;
  const int j = lane & 15, kg = lane >> 4;
  const int aoff = j * 1024 + w * 256 + kg * 8;
  const int erow = tid >> 2, euu = tid & 3;
  const int eu = u0 + euu;

  // ---- layer 0: h0(s) ----
  if (s < 256) {
    f32x4 acc[4] = {};
    if (s > 0) {
      const f16* ap = A1 + (size_t)(s - 1) * 65536 + aoff;
#pragma unroll
      for (int kt = 0; kt < 8; ++kt)
#pragma unroll
        for (int mf = 0; mf < 4; ++mf)
          acc[mf] = mfma16x32(*(const f16x8*)(ap + mf * 16384 + kt * 32),
                              bvU0[kt], acc[mf]);
    }
#pragma unroll
    for (int mf = 0; mf < 4; ++mf)
#pragma unroll
      for (int r = 0; r < 4; ++r)
        zred[w * 1088 + (mf * 16 + kg * 4 + r) * 17 + j] = acc[mf][r];
    __syncthreads();

    float z[4];
#pragma unroll
    for (int g = 0; g < 4; ++g) {
      float sm = xz[g];
#pragma unroll
      for (int wv = 0; wv < 4; ++wv)
        sm += zred[wv * 1088 + erow * 17 + g * 4 + euu];
      z[g] = sm;
    }
    float gi = sigmoidf_(z[0]), gf = sigmoidf_(z[1]);
    float gg = tanhf(z[2]), go = sigmoidf_(z[3]);
    c0 = gf * c0 + gi * gg;
    A1[(size_t)(s * 64 + erow) * 1024 + eu] = (f16)(go * tanhf(c0));
  }
  __syncthreads();  // zred reuse guard between phases

  // ---- layer 1: h1(t), t = s-1 ----
  if (s >= 1) {
    const int t = s - 1;
    f32x4 acc[4] = {};
    const f16* ap = A1 + (size_t)t * 65536 + aoff;  // h0(t), synced last step
#pragma unroll
    for (int kt = 0; kt < 8; ++kt)
#pragma unroll
      for (int mf = 0; mf < 4; ++mf)
        acc[mf] = mfma16x32(*(const f16x8*)(ap + mf * 16384 + kt * 32),
                            bvW1[kt], acc[mf]);
    if (t > 0) {
      const f16* hp = ((t & 1) ? H1a : H1b) + aoff;  // h1(t-1)
#pragma unroll
      for (int kt = 0; kt < 8; ++kt)
#pragma unroll
        for (int mf = 0; mf < 4; ++mf)
          acc[mf] = mfma16x32(*(const f16x8*)(hp + mf * 16384 + kt * 32),
                              bvU1[kt], acc[mf]);
    }
#pragma unroll
    for (int mf = 0; mf < 4; ++mf)
#pragma unroll
      for (int r = 0; r < 4; ++r)
        zred[w * 1088 + (mf * 16 + kg * 4 + r) * 17 + j] = acc[mf][r];
    __syncthreads();

    float z[4];
#pragma unroll
    for (int g = 0; g < 4; ++g) {
      float sm = bias1[g];
#pragma unroll
      for (int wv = 0; wv < 4; ++wv)
        sm += zred[wv * 1088 + erow * 17 + g * 4 + euu];
      z[g] = sm;
    }
    float gi = sigmoidf_(z[0]), gf = sigmoidf_(z[1]);
    float gg = tanhf(z[2]), go = sigmoidf_(z[3]);
    c1 = gf * c1 + gi * gg;
    float hn = go * tanhf(c1);
    f16* hw = (t & 1) ? H1b : H1a;
    hw[erow * 1024 + eu] = (f16)hn;
    out[(size_t)erow * 262144 + (size_t)t * 1024 + eu] = hn;
    if (t == 255) {
      out[16777216 + erow * 1024 + eu] = hn;
      out[16777216 + 65536 + erow * 1024 + eu] = c1;
    }
  }
}

#define SCAN_ARGS                                                           \
  const f16* __restrict__ XZ, const f16* __restrict__ U0t,                  \
      const f16* __restrict__ W1t, const f16* __restrict__ U1t,             \
      const float* __restrict__ b1, f16* __restrict__ A1,                   \
      f16* __restrict__ H1a, f16* __restrict__ H1b, float* __restrict__ C0, \
      float* __restrict__ C1, float* __restrict__ out

#define PRELOAD_WEIGHTS                                                 \
  const int tid_ = threadIdx.x, lane_ = tid_ & 63, w_ = tid_ >> 6;      \
  const int u0 = blockIdx.x * 4;                                       \
  const int j_ = lane_ & 15, kg_ = lane_ >> 4;                          \
  const int ncol_ = (j_ >> 2) * 1024 + u0 + (j_ & 3);                   \
  const int woff_ = ncol_ * 1024 + w_ * 256 + kg_ * 8;                  \
  f16x8 bvU0[8], bvW1[8], bvU1[8];                                      \
  _Pragma("unroll") for (int kt = 0; kt < 8; ++kt) {                    \
    bvU0[kt] = *(const f16x8*)(U0t + woff_ + kt * 32);                  \
    bvW1[kt] = *(const f16x8*)(W1t + woff_ + kt * 32);                  \
    bvU1[kt] = *(const f16x8*)(U1t + woff_ + kt * 32);                  \
  }                                                                     \
  const int erow_ = tid_ >> 2;                                          \
  const int eu_ = u0 + (tid_ & 3);                                      \
  float bias1[4];                                                       \
  _Pragma("unroll") for (int g = 0; g < 4; ++g) bias1[g] =              \
      b1[g * 1024 + eu_];

// persistent cooperative version: 256 blocks (1/CU), 256 grid barriers
__global__ __launch_bounds__(256, 1) void k_scan(SCAN_ARGS, unsigned* arr,
                                                 unsigned* rel) {
  __shared__ float zred[4352];
  PRELOAD_WEIGHTS
  (void)C0; (void)C1;
  float c0 = 0.0f, c1 = 0.0f;  // cell state in registers for the whole scan
  // xz gate values for step 0
  float xz[4];
#pragma unroll
  for (int g = 0; g < 4; ++g)
    xz[g] = (float)XZ[(size_t)erow_ * 4096 + g * 1024 + eu_];

  for (int s = 0; s <= 256; ++s) {
    step_once(s, u0, bvU0, bvW1, bvU1, bias1, xz, A1, H1a, H1b, c0, c1, out,
              zred);
    // prefetch next step's xz so load latency hides under the barrier wait
    float xzn[4] = {0.f, 0.f, 0.f, 0.f};
    if (s + 1 < 256) {
      const f16* xrow = XZ + (size_t)((s + 1) * 64 + erow_) * 4096;
#pragma unroll
      for (int g = 0; g < 4; ++g) xzn[g] = (float)xrow[g * 1024 + eu_];
    }
    if (s < 256) grid_barrier3(arr, rel, s);
#pragma unroll
    for (int g = 0; g < 4; ++g) xz[g] = xzn[g];
  }
}

// fallback: one step per launch (kernel boundary = barrier), identical math,
// cell state in global C0/C1 (memset to zero before step 0)
__global__ __launch_bounds__(256, 1) void k_step(SCAN_ARGS, int s) {
  __shared__ float zred[4352];
  PRELOAD_WEIGHTS
  float xz[4] = {0.f, 0.f, 0.f, 0.f};
  if (s < 256) {
    const f16* xrow = XZ + (size_t)(s * 64 + erow_) * 4096;
#pragma unroll
    for (int g = 0; g < 4; ++g) xz[g] = (float)xrow[g * 1024 + eu_];
  }
  float c0 = C0[erow_ * 1024 + eu_];
  float c1 = C1[erow_ * 1024 + eu_];
  step_once(s, u0, bvU0, bvW1, bvU1, bias1, xz, A1, H1a, H1b, c0, c1, out,
            zred);
  C0[erow_ * 1024 + eu_] = c0;
  C1[erow_ * 1024 + eu_] = c1;
}

extern "C" void kernel_launch(void* const* d_in, const int* in_sizes, int n_in,
                              void* d_out, int out_size, void* d_ws, size_t ws_size,
                              hipStream_t stream) {
  (void)in_sizes; (void)n_in; (void)out_size; (void)ws_size;
  const int* tokens = (const int*)d_in[0];
  const float* emb = (const float*)d_in[1];
  const float* W0 = (const float*)d_in[2];
  const float* U0 = (const float*)d_in[3];
  const float* b0 = (const float*)d_in[4];
  const float* W1 = (const float*)d_in[5];
  const float* U1 = (const float*)d_in[6];
  const float* b1 = (const float*)d_in[7];
  float* out = (float*)d_out;

  // workspace carve-up
  char* p = (char*)d_ws;
  f16* A0 = (f16*)p;   p += (size_t)16384 * 512 * 2;    // x tokens, fp16
  f16* A1 = (f16*)p;   p += (size_t)16384 * 1024 * 2;   // h0 history, fp16
  f16* W0t = (f16*)p;  p += (size_t)4096 * 512 * 2;     // W0^T
  f16* U0t = (f16*)p;  p += (size_t)4096 * 1024 * 2;    // U0^T
  f16* W1t = (f16*)p;  p += (size_t)4096 * 1024 * 2;    // W1^T
  f16* U1t = (f16*)p;  p += (size_t)4096 * 1024 * 2;    // U1^T
  f16* XZ = (f16*)p;   p += (size_t)16384 * 4096 * 2;   // xz0, rows t*64+b
  f16* H1a = (f16*)p;  p += 64 * 1024 * 2;              // h1 ping
  f16* H1b = (f16*)p;  p += 64 * 1024 * 2;              // h1 pong
  float* C0 = (float*)p; p += 64 * 1024 * 4;            // cell state L0 (fallback)
  float* C1 = (float*)p; p += 64 * 1024 * 4;            // cell state L1 (fallback)
  unsigned* arr = (unsigned*)p; p += 256 * 32 * 4;      // arrive lines
  unsigned* rel = (unsigned*)p; p += 256 * 32 * 4;      // release lines

  // weight transposes + casts
  k_transpose_f16<<<512, 256, 0, stream>>>(W0, W0t, 512, 4096);
  k_transpose_f16<<<1024, 256, 0, stream>>>(U0, U0t, 1024, 4096);
  k_transpose_f16<<<1024, 256, 0, stream>>>(W1, W1t, 1024, 4096);
  k_transpose_f16<<<1024, 256, 0, stream>>>(U1, U1t, 1024, 4096);

  // embedding
  k_embed_f16<<<8192, 256, 0, stream>>>(tokens, emb, A0);

  // layer 0 input projection: xz0 = x @ W0 + b0
  k_gemm_f16<<<4096, 256, 0, stream>>>(A0, W0t, b0, XZ, 16384, 4096, 512);

  // zero the state the scan reads
  hipMemsetAsync(C0, 0, 64 * 1024 * 4 * 2, stream);        // C0+C1
  hipMemsetAsync(arr, 0, 256 * 32 * 4 * 2, stream);        // arr+rel

  // persistent pipelined scan; checked launch + deterministic fallback
  const f16* XZc = XZ; const f16* U0c = U0t; const f16* W1c = W1t;
  const f16* U1c = U1t; const float* b1c = b1;
  f16* A1p = A1; f16* H1ap = H1a; f16* H1bp = H1b;
  float* C0p = C0; float* C1p = C1; float* outp = out;
  unsigned* ar = arr; unsigned* rl = rel;
  void* kargs[] = {(void*)&XZc, (void*)&U0c, (void*)&W1c, (void*)&U1c,
                   (void*)&b1c, (void*)&A1p, (void*)&H1ap, (void*)&H1bp,
                   (void*)&C0p, (void*)&C1p, (void*)&outp, (void*)&ar,
                   (void*)&rl};
  hipError_t e = hipLaunchCooperativeKernel((const void*)k_scan, dim3(256),
                                            dim3(256), kargs, 0, stream);
  if (e != hipSuccess) {
    (void)hipGetLastError();  // clear error state; run per-step fallback
    for (int s = 0; s <= 256; ++s)
      k_step<<<256, 256, 0, stream>>>(XZ, U0t, W1t, U1t, b1, A1, H1a, H1b,
                                      C0, C1, out, s);
  }
}

// Round 6
// 4198.674 us; speedup vs baseline: 4.8124x; 3.0946x over previous
//
#include <hip/hip_runtime.h>

// LSTM encoder: V=32000 E=512 U=1024 L=2, B=64 T=256.
// Round 6: persistent cooperative scan with NO threadfence. Cross-block h
// data is written with sc0/sc1 write-through stores (visible at L3 without
// buffer_wbl2) to write-once per-step slots (A1[s], H1hist[t]) so readers
// can never hit a stale cached line (no buffer_inv needed). Barrier =
// s_waitcnt vmcnt(0) + relaxed-agent flag stores/polls (proven in r5).
// Rounds 3/4/5 burned 50-78us/step on per-step __threadfence L2
// writeback/invalidate storms (512 full-L2 wbl2+inv per step).

typedef _Float16 f16;
typedef _Float16 f16x8 __attribute__((ext_vector_type(8)));
typedef _Float16 f16x4 __attribute__((ext_vector_type(4)));
typedef float f32x4 __attribute__((ext_vector_type(4)));

__device__ __forceinline__ f32x4 mfma16x32(f16x8 a, f16x8 b, f32x4 c) {
  return __builtin_amdgcn_mfma_f32_16x16x32_f16(a, b, c, 0, 0, 0);
}

__device__ __forceinline__ void gl_lds16(const void* g, void* l) {
  __builtin_amdgcn_global_load_lds(
      (const __attribute__((address_space(1))) void*)g,
      (__attribute__((address_space(3))) void*)l, 16, 0, 0);
}

__device__ __forceinline__ float sigmoidf_(float x) {
  return 1.0f / (1.0f + expf(-x));
}

// write-through f16 store: lands at the L3 coherence point, no dirty L2 line
__device__ __forceinline__ void st_f16_sc(f16* p, float v) {
  f16 h = (f16)v;
  unsigned u = (unsigned)__builtin_bit_cast(unsigned short, h);
  asm volatile("global_store_short %0, %1, off sc0 sc1"
               :: "v"(p), "v"(u) : "memory");
}

// ---------- transpose + cast: D[n][k] = (f16)S[k][n] ----------
__global__ __launch_bounds__(256) void k_transpose_f16(
    const float* __restrict__ S, f16* __restrict__ D, int K, int N) {
  __shared__ float tile[64][65];
  int nk = K >> 6;
  int k0 = (blockIdx.x % nk) << 6;
  int n0 = (blockIdx.x / nk) << 6;
  int tc = threadIdx.x & 63;
  int tq = threadIdx.x >> 6;
#pragma unroll
  for (int r = 0; r < 16; ++r) {
    int kk = tq * 16 + r;
    tile[kk][tc] = S[(size_t)(k0 + kk) * N + (n0 + tc)];
  }
  __syncthreads();
#pragma unroll
  for (int r = 0; r < 16; ++r) {
    int nn = tq * 16 + r;
    D[(size_t)(n0 + nn) * K + (k0 + tc)] = (f16)tile[tc][nn];
  }
}

// ---------- embedding lookup -> fp16 A0[m][512], row m = t*64 + b ----------
__global__ __launch_bounds__(256) void k_embed_f16(
    const int* __restrict__ tok, const float* __restrict__ emb,
    f16* __restrict__ A0) {
  int i = blockIdx.x * 256 + threadIdx.x;
  int m = i >> 7;
  int e = (i & 127) << 2;
  int t = m >> 6, b = m & 63;
  int tk = tok[b * 256 + t];
  const float4 v = *(const float4*)(emb + (size_t)tk * 512 + e);
  f16x4 o = {(f16)v.x, (f16)v.y, (f16)v.z, (f16)v.w};
  *(f16x4*)(A0 + (size_t)m * 512 + e) = o;
}

// ---------- C[m][n] = (f16)(sum_k A[m][k]*Bt[n][k] + bias[n]) ----------
__global__ __launch_bounds__(256) void k_gemm_f16(
    const f16* __restrict__ A, const f16* __restrict__ Bt,
    const float* __restrict__ bias, f16* __restrict__ C,
    int M, int N, int K) {
  __shared__ f16 sA[2][128 * 32];
  __shared__ f16 sB[2][128 * 32];
  const int tid = threadIdx.x, lane = tid & 63, w = tid >> 6;
  const int mb = M >> 7;
  const int bm = blockIdx.x % mb, bn = blockIdx.x / mb;
  const int am0 = bm << 7, bn0 = bn << 7;
  const int wm = w >> 1, wn = w & 1;
  const int srow = lane >> 2, sch = lane & 3;

  f32x4 acc[4][4] = {};
  const int NT = K >> 5;
  int cur = 0;

  auto stage = [&](int kt, int buf) {
#pragma unroll
    for (int q2 = 0; q2 < 2; ++q2) {
      int q = w * 2 + q2;
      int row = q * 16 + srow;
      const f16* ga = A + (size_t)(am0 + row) * K + kt * 32 + sch * 8;
      const f16* gb = Bt + (size_t)(bn0 + row) * K + kt * 32 + sch * 8;
      gl_lds16(ga, (char*)&sA[buf][0] + q * 1024);
      gl_lds16(gb, (char*)&sB[buf][0] + q * 1024);
    }
  };

  stage(0, 0);
  __syncthreads();
  for (int kt = 0; kt < NT; ++kt) {
    if (kt + 1 < NT) stage(kt + 1, cur ^ 1);
    const f16* pa = &sA[cur][(wm * 64 + (lane & 15)) * 32 + (lane >> 4) * 8];
    const f16* pb = &sB[cur][(wn * 64 + (lane & 15)) * 32 + (lane >> 4) * 8];
    f16x8 av[4], bv[4];
#pragma unroll
    for (int mf = 0; mf < 4; ++mf) av[mf] = *(const f16x8*)(pa + mf * 512);
#pragma unroll
    for (int nf = 0; nf < 4; ++nf) bv[nf] = *(const f16x8*)(pb + nf * 512);
#pragma unroll
    for (int mf = 0; mf < 4; ++mf)
#pragma unroll
      for (int nf = 0; nf < 4; ++nf)
        acc[mf][nf] = mfma16x32(av[mf], bv[nf], acc[mf][nf]);
    __syncthreads();
    cur ^= 1;
  }

#pragma unroll
  for (int mf = 0; mf < 4; ++mf)
#pragma unroll
    for (int nf = 0; nf < 4; ++nf) {
      int col = bn0 + wn * 64 + nf * 16 + (lane & 15);
      float bs = bias[col];
#pragma unroll
      for (int r = 0; r < 4; ++r) {
        int row = am0 + wm * 64 + mf * 16 + (lane >> 4) * 4 + r;
        C[(size_t)row * N + col] = (f16)(acc[mf][nf][r] + bs);
      }
    }
}

// ---------- fence-free grid barrier ----------
// Precondition: all cross-block data this step was written via sc0/sc1
// write-through stores. s_waitcnt vmcnt(0) => those stores reached L3.
// Flags are relaxed AGENT atomics (sc1: L2-bypass) on 1-writer/1-reader
// lines with monotonic values; stale reads only delay, never corrupt.
__device__ __forceinline__ void grid_barrier4(unsigned* arr, unsigned* rel,
                                              int s) {
  asm volatile("s_waitcnt vmcnt(0)" ::: "memory");
  __syncthreads();  // every wave's write-through stores are at L3
  const unsigned v = (unsigned)s + 1u;
  const int bid = blockIdx.x, tid = threadIdx.x;
  if (bid == 0) {
    if (tid > 0) {
      while (__hip_atomic_load(&arr[(unsigned)tid * 32u], __ATOMIC_RELAXED,
                               __HIP_MEMORY_SCOPE_AGENT) < v)
        __builtin_amdgcn_s_sleep(1);
    }
    __syncthreads();  // all 255 arrivals observed
    if (tid > 0)
      __hip_atomic_store(&rel[(unsigned)tid * 32u], v, __ATOMIC_RELAXED,
                         __HIP_MEMORY_SCOPE_AGENT);
  } else {
    if (tid == 0) {
      __hip_atomic_store(&arr[(unsigned)bid * 32u], v, __ATOMIC_RELAXED,
                         __HIP_MEMORY_SCOPE_AGENT);
      while (__hip_atomic_load(&rel[(unsigned)bid * 32u], __ATOMIC_RELAXED,
                               __HIP_MEMORY_SCOPE_AGENT) < v)
        __builtin_amdgcn_s_sleep(1);
    }
    __syncthreads();
  }
}

// ---------- one pipelined step ----------
// L0 computes h0(s) (s<256); L1 computes h1(t=s-1) (s>=1). The U0-part and
// W1-part both consume A1[s-1]: fused into one pass sharing A-fragment loads.
// All h outputs stored write-through (st_f16_sc) to write-once slots.
__device__ __forceinline__ void step_once(
    int s, int u0, const f16x8 bvU0[8], const f16x8 bvW1[8],
    const f16x8 bvU1[8], const float bias1[4], const float xz[4],
    f16* __restrict__ A1, f16* __restrict__ H1h, int hmask,
    float& c0, float& c1, float* __restrict__ out, float* zred) {
  const int tid = threadIdx.x, lane = tid & 63, w = tid >> 6;
  const int j = lane & 15, kg = lane >> 4;
  const int aoff = j * 1024 + w * 256 + kg * 8;
  const int erow = tid >> 2, euu = tid & 3;
  const int eu = u0 + euu;

  f32x4 accA[4] = {};  // z0 partials (U0 over h0(s-1))
  f32x4 accB[4] = {};  // z1 partials (W1 over h0(t) + U1 over h1(t-1))

  if (s >= 1) {
    const f16* ap = A1 + (size_t)(s - 1) * 65536 + aoff;
#pragma unroll
    for (int kt = 0; kt < 8; ++kt)
#pragma unroll
      for (int mf = 0; mf < 4; ++mf) {
        f16x8 av = *(const f16x8*)(ap + mf * 16384 + kt * 32);
        if (s < 256) accA[mf] = mfma16x32(av, bvU0[kt], accA[mf]);
        accB[mf] = mfma16x32(av, bvW1[kt], accB[mf]);
      }
    if (s >= 2) {
      const f16* hp = H1h + (size_t)((s - 2) & hmask) * 65536 + aoff;
#pragma unroll
      for (int kt = 0; kt < 8; ++kt)
#pragma unroll
        for (int mf = 0; mf < 4; ++mf)
          accB[mf] = mfma16x32(*(const f16x8*)(hp + mf * 16384 + kt * 32),
                               bvU1[kt], accB[mf]);
    }
  }

  // ---- L0 finish: z0 = xz + reduce(accA); gates; h0(s) ----
  if (s < 256) {
#pragma unroll
    for (int mf = 0; mf < 4; ++mf)
#pragma unroll
      for (int r = 0; r < 4; ++r)
        zred[w * 1088 + (mf * 16 + kg * 4 + r) * 17 + j] = accA[mf][r];
    __syncthreads();
    float z[4];
#pragma unroll
    for (int g = 0; g < 4; ++g) {
      float sm = xz[g];
#pragma unroll
      for (int wv = 0; wv < 4; ++wv)
        sm += zred[wv * 1088 + erow * 17 + g * 4 + euu];
      z[g] = sm;
    }
    float gi = sigmoidf_(z[0]), gf = sigmoidf_(z[1]);
    float gg = tanhf(z[2]), go = sigmoidf_(z[3]);
    c0 = gf * c0 + gi * gg;
    st_f16_sc(&A1[(size_t)(s * 64 + erow) * 1024 + eu], go * tanhf(c0));
  }
  __syncthreads();  // zred reuse guard

  // ---- L1 finish: z1 = b1 + reduce(accB); gates; h1(t) ----
  if (s >= 1) {
    const int t = s - 1;
#pragma unroll
    for (int mf = 0; mf < 4; ++mf)
#pragma unroll
      for (int r = 0; r < 4; ++r)
        zred[w * 1088 + (mf * 16 + kg * 4 + r) * 17 + j] = accB[mf][r];
    __syncthreads();
    float z[4];
#pragma unroll
    for (int g = 0; g < 4; ++g) {
      float sm = bias1[g];
#pragma unroll
      for (int wv = 0; wv < 4; ++wv)
        sm += zred[wv * 1088 + erow * 17 + g * 4 + euu];
      z[g] = sm;
    }
    float gi = sigmoidf_(z[0]), gf = sigmoidf_(z[1]);
    float gg = tanhf(z[2]), go = sigmoidf_(z[3]);
    c1 = gf * c1 + gi * gg;
    float hn = go * tanhf(c1);
    st_f16_sc(&H1h[(size_t)(t & hmask) * 65536 + erow * 1024 + eu], hn);
    out[(size_t)erow * 262144 + (size_t)t * 1024 + eu] = hn;
    if (t == 255) {
      out[16777216 + erow * 1024 + eu] = hn;
      out[16777216 + 65536 + erow * 1024 + eu] = c1;
    }
  }
}

#define SCAN_ARGS                                                            \
  const f16* __restrict__ XZ, const f16* __restrict__ U0t,                   \
      const f16* __restrict__ W1t, const f16* __restrict__ U1t,              \
      const float* __restrict__ b1, f16* __restrict__ A1,                    \
      f16* __restrict__ H1h, float* __restrict__ C0, float* __restrict__ C1, \
      float* __restrict__ out

#define PRELOAD_WEIGHTS                                                 \
  const int tid_ = threadIdx.x, lane_ = tid_ & 63, w_ = tid_ >> 6;      \
  const int u0 = blockIdx.x * 4;                                        \
  const int j_ = lane_ & 15, kg_ = lane_ >> 4;                          \
  const int ncol_ = (j_ >> 2) * 1024 + u0 + (j_ & 3);                   \
  const int woff_ = ncol_ * 1024 + w_ * 256 + kg_ * 8;                  \
  f16x8 bvU0[8], bvW1[8], bvU1[8];                                      \
  _Pragma("unroll") for (int kt = 0; kt < 8; ++kt) {                    \
    bvU0[kt] = *(const f16x8*)(U0t + woff_ + kt * 32);                  \
    bvW1[kt] = *(const f16x8*)(W1t + woff_ + kt * 32);                  \
    bvU1[kt] = *(const f16x8*)(U1t + woff_ + kt * 32);                  \
  }                                                                     \
  const int erow_ = tid_ >> 2;                                          \
  const int eu_ = u0 + (tid_ & 3);                                      \
  float bias1[4];                                                       \
  _Pragma("unroll") for (int g = 0; g < 4; ++g) bias1[g] =              \
      b1[g * 1024 + eu_];

// persistent cooperative version: 256 blocks (1/CU), 256 grid barriers,
// H1 slots fresh per step (hmask=255), cell state in registers
__global__ __launch_bounds__(256, 1) void k_scan(SCAN_ARGS, unsigned* arr,
                                                 unsigned* rel) {
  __shared__ float zred[4352];
  PRELOAD_WEIGHTS
  (void)C0; (void)C1;
  float c0 = 0.0f, c1 = 0.0f;
  float xz[4];
#pragma unroll
  for (int g = 0; g < 4; ++g)
    xz[g] = (float)XZ[(size_t)erow_ * 4096 + g * 1024 + eu_];

  for (int s = 0; s <= 256; ++s) {
    step_once(s, u0, bvU0, bvW1, bvU1, bias1, xz, A1, H1h, 255, c0, c1, out,
              zred);
    float xzn[4] = {0.f, 0.f, 0.f, 0.f};
    if (s + 1 < 256) {
      const f16* xrow = XZ + (size_t)((s + 1) * 64 + erow_) * 4096;
#pragma unroll
      for (int g = 0; g < 4; ++g) xzn[g] = (float)xrow[g * 1024 + eu_];
    }
    if (s < 256) grid_barrier4(arr, rel, s);
#pragma unroll
    for (int g = 0; g < 4; ++g) xz[g] = xzn[g];
  }
}

// fallback: one step per launch (kernel boundary = sync + flush), identical
// math, H1 ping-pong (hmask=1), cell state in global C0/C1
__global__ __launch_bounds__(256, 1) void k_step(SCAN_ARGS, int s) {
  __shared__ float zred[4352];
  PRELOAD_WEIGHTS
  float xz[4] = {0.f, 0.f, 0.f, 0.f};
  if (s < 256) {
    const f16* xrow = XZ + (size_t)(s * 64 + erow_) * 4096;
#pragma unroll
    for (int g = 0; g < 4; ++g) xz[g] = (float)xrow[g * 1024 + eu_];
  }
  float c0 = C0[erow_ * 1024 + eu_];
  float c1 = C1[erow_ * 1024 + eu_];
  step_once(s, u0, bvU0, bvW1, bvU1, bias1, xz, A1, H1h, 1, c0, c1, out,
            zred);
  C0[erow_ * 1024 + eu_] = c0;
  C1[erow_ * 1024 + eu_] = c1;
}

extern "C" void kernel_launch(void* const* d_in, const int* in_sizes, int n_in,
                              void* d_out, int out_size, void* d_ws, size_t ws_size,
                              hipStream_t stream) {
  (void)in_sizes; (void)n_in; (void)out_size;
  const int* tokens = (const int*)d_in[0];
  const float* emb = (const float*)d_in[1];
  const float* W0 = (const float*)d_in[2];
  const float* U0 = (const float*)d_in[3];
  const float* b0 = (const float*)d_in[4];
  const float* W1 = (const float*)d_in[5];
  const float* U1 = (const float*)d_in[6];
  const float* b1 = (const float*)d_in[7];
  float* out = (float*)d_out;

  // workspace carve-up; H1h LAST so the fallback (2 slots) footprint equals
  // the round-5-proven 214.7 MB while the coop path (256 slots) needs 248 MB.
  char* p = (char*)d_ws;
  f16* A0 = (f16*)p;   p += (size_t)16384 * 512 * 2;    // x tokens, fp16
  f16* A1 = (f16*)p;   p += (size_t)16384 * 1024 * 2;   // h0 history
  f16* W0t = (f16*)p;  p += (size_t)4096 * 512 * 2;     // W0^T
  f16* U0t = (f16*)p;  p += (size_t)4096 * 1024 * 2;    // U0^T
  f16* W1t = (f16*)p;  p += (size_t)4096 * 1024 * 2;    // W1^T
  f16* U1t = (f16*)p;  p += (size_t)4096 * 1024 * 2;    // U1^T
  f16* XZ = (f16*)p;   p += (size_t)16384 * 4096 * 2;   // xz0, rows t*64+b
  float* C0 = (float*)p; p += 64 * 1024 * 4;            // cell L0 (fallback)
  float* C1 = (float*)p; p += 64 * 1024 * 4;            // cell L1 (fallback)
  unsigned* arr = (unsigned*)p; p += 256 * 32 * 4;      // arrive lines
  unsigned* rel = (unsigned*)p; p += 256 * 32 * 4;      // release lines
  f16* H1h = (f16*)p;                                   // h1 history slots
  const size_t need_coop = (size_t)(p - (char*)d_ws) + (size_t)256 * 65536 * 2;

  // weight transposes + casts
  k_transpose_f16<<<512, 256, 0, stream>>>(W0, W0t, 512, 4096);
  k_transpose_f16<<<1024, 256, 0, stream>>>(U0, U0t, 1024, 4096);
  k_transpose_f16<<<1024, 256, 0, stream>>>(W1, W1t, 1024, 4096);
  k_transpose_f16<<<1024, 256, 0, stream>>>(U1, U1t, 1024, 4096);

  // embedding
  k_embed_f16<<<8192, 256, 0, stream>>>(tokens, emb, A0);

  // layer 0 input projection: xz0 = x @ W0 + b0
  k_gemm_f16<<<4096, 256, 0, stream>>>(A0, W0t, b0, XZ, 16384, 4096, 512);

  hipMemsetAsync(C0, 0, 64 * 1024 * 4 * 2, stream);  // C0+C1
  hipMemsetAsync(arr, 0, 256 * 32 * 4 * 2, stream);  // arr+rel

  bool coop_ok = (ws_size >= need_coop);
  if (coop_ok) {
    const f16* XZc = XZ; const f16* U0c = U0t; const f16* W1c = W1t;
    const f16* U1c = U1t; const float* b1c = b1;
    f16* A1p = A1; f16* H1p = H1h;
    float* C0p = C0; float* C1p = C1; float* outp = out;
    unsigned* ar = arr; unsigned* rl = rel;
    void* kargs[] = {(void*)&XZc, (void*)&U0c, (void*)&W1c, (void*)&U1c,
                     (void*)&b1c, (void*)&A1p, (void*)&H1p, (void*)&C0p,
                     (void*)&C1p, (void*)&outp, (void*)&ar, (void*)&rl};
    hipError_t e = hipLaunchCooperativeKernel((const void*)k_scan, dim3(256),
                                              dim3(256), kargs, 0, stream);
    if (e != hipSuccess) {
      (void)hipGetLastError();
      coop_ok = false;
    }
  }
  if (!coop_ok) {
    for (int s = 0; s <= 256; ++s)
      k_step<<<256, 256, 0, stream>>>(XZ, U0t, W1t, U1t, b1, A1, H1h, C0, C1,
                                      out, s);
  }
}

// Round 7
// 3780.045 us; speedup vs baseline: 5.3454x; 1.1107x over previous
//
#include <hip/hip_runtime.h>

// LSTM encoder: V=32000 E=512 U=1024 L=2, B=64 T=256.
// Round 7: fence-free persistent scan (r6 barrier) + 512-block role-split:
// blocks 0-255 compute layer 0, blocks 256-511 compute layer 1 concurrently
// (2 blocks/CU, 2 waves/SIMD -> latency hiding; r6 ran 1 wave/SIMD, fully
// stall-serialized at 16.2us/step).

typedef _Float16 f16;
typedef _Float16 f16x8 __attribute__((ext_vector_type(8)));
typedef _Float16 f16x4 __attribute__((ext_vector_type(4)));
typedef float f32x4 __attribute__((ext_vector_type(4)));

__device__ __forceinline__ f32x4 mfma16x32(f16x8 a, f16x8 b, f32x4 c) {
  return __builtin_amdgcn_mfma_f32_16x16x32_f16(a, b, c, 0, 0, 0);
}

__device__ __forceinline__ void gl_lds16(const void* g, void* l) {
  __builtin_amdgcn_global_load_lds(
      (const __attribute__((address_space(1))) void*)g,
      (__attribute__((address_space(3))) void*)l, 16, 0, 0);
}

__device__ __forceinline__ float sigmoidf_(float x) {
  return 1.0f / (1.0f + expf(-x));
}

// write-through f16 store: lands at the L3 coherence point, no dirty L2 line
__device__ __forceinline__ void st_f16_sc(f16* p, float v) {
  f16 h = (f16)v;
  unsigned u = (unsigned)__builtin_bit_cast(unsigned short, h);
  asm volatile("global_store_short %0, %1, off sc0 sc1"
               :: "v"(p), "v"(u) : "memory");
}

// ---------- transpose + cast: D[n][k] = (f16)S[k][n] ----------
__global__ __launch_bounds__(256) void k_transpose_f16(
    const float* __restrict__ S, f16* __restrict__ D, int K, int N) {
  __shared__ float tile[64][65];
  int nk = K >> 6;
  int k0 = (blockIdx.x % nk) << 6;
  int n0 = (blockIdx.x / nk) << 6;
  int tc = threadIdx.x & 63;
  int tq = threadIdx.x >> 6;
#pragma unroll
  for (int r = 0; r < 16; ++r) {
    int kk = tq * 16 + r;
    tile[kk][tc] = S[(size_t)(k0 + kk) * N + (n0 + tc)];
  }
  __syncthreads();
#pragma unroll
  for (int r = 0; r < 16; ++r) {
    int nn = tq * 16 + r;
    D[(size_t)(n0 + nn) * K + (k0 + tc)] = (f16)tile[tc][nn];
  }
}

// ---------- embedding lookup -> fp16 A0[m][512], row m = t*64 + b ----------
__global__ __launch_bounds__(256) void k_embed_f16(
    const int* __restrict__ tok, const float* __restrict__ emb,
    f16* __restrict__ A0) {
  int i = blockIdx.x * 256 + threadIdx.x;
  int m = i >> 7;
  int e = (i & 127) << 2;
  int t = m >> 6, b = m & 63;
  int tk = tok[b * 256 + t];
  const float4 v = *(const float4*)(emb + (size_t)tk * 512 + e);
  f16x4 o = {(f16)v.x, (f16)v.y, (f16)v.z, (f16)v.w};
  *(f16x4*)(A0 + (size_t)m * 512 + e) = o;
}

// ---------- C[m][n] = (f16)(sum_k A[m][k]*Bt[n][k] + bias[n]) ----------
__global__ __launch_bounds__(256) void k_gemm_f16(
    const f16* __restrict__ A, const f16* __restrict__ Bt,
    const float* __restrict__ bias, f16* __restrict__ C,
    int M, int N, int K) {
  __shared__ f16 sA[2][128 * 32];
  __shared__ f16 sB[2][128 * 32];
  const int tid = threadIdx.x, lane = tid & 63, w = tid >> 6;
  const int mb = M >> 7;
  const int bm = blockIdx.x % mb, bn = blockIdx.x / mb;
  const int am0 = bm << 7, bn0 = bn << 7;
  const int wm = w >> 1, wn = w & 1;
  const int srow = lane >> 2, sch = lane & 3;

  f32x4 acc[4][4] = {};
  const int NT = K >> 5;
  int cur = 0;

  auto stage = [&](int kt, int buf) {
#pragma unroll
    for (int q2 = 0; q2 < 2; ++q2) {
      int q = w * 2 + q2;
      int row = q * 16 + srow;
      const f16* ga = A + (size_t)(am0 + row) * K + kt * 32 + sch * 8;
      const f16* gb = Bt + (size_t)(bn0 + row) * K + kt * 32 + sch * 8;
      gl_lds16(ga, (char*)&sA[buf][0] + q * 1024);
      gl_lds16(gb, (char*)&sB[buf][0] + q * 1024);
    }
  };

  stage(0, 0);
  __syncthreads();
  for (int kt = 0; kt < NT; ++kt) {
    if (kt + 1 < NT) stage(kt + 1, cur ^ 1);
    const f16* pa = &sA[cur][(wm * 64 + (lane & 15)) * 32 + (lane >> 4) * 8];
    const f16* pb = &sB[cur][(wn * 64 + (lane & 15)) * 32 + (lane >> 4) * 8];
    f16x8 av[4], bv[4];
#pragma unroll
    for (int mf = 0; mf < 4; ++mf) av[mf] = *(const f16x8*)(pa + mf * 512);
#pragma unroll
    for (int nf = 0; nf < 4; ++nf) bv[nf] = *(const f16x8*)(pb + nf * 512);
#pragma unroll
    for (int mf = 0; mf < 4; ++mf)
#pragma unroll
      for (int nf = 0; nf < 4; ++nf)
        acc[mf][nf] = mfma16x32(av[mf], bv[nf], acc[mf][nf]);
    __syncthreads();
    cur ^= 1;
  }

#pragma unroll
  for (int mf = 0; mf < 4; ++mf)
#pragma unroll
    for (int nf = 0; nf < 4; ++nf) {
      int col = bn0 + wn * 64 + nf * 16 + (lane & 15);
      float bs = bias[col];
#pragma unroll
      for (int r = 0; r < 4; ++r) {
        int row = am0 + wm * 64 + mf * 16 + (lane >> 4) * 4 + r;
        C[(size_t)row * N + col] = (f16)(acc[mf][nf][r] + bs);
      }
    }
}

// ---------- fence-free grid barrier, 512 blocks ----------
// Precondition: cross-block data written via sc0/sc1 write-through stores;
// s_waitcnt vmcnt(0) => at L3. Flags: relaxed AGENT atomics, 1-writer/
// 1-reader lines, monotonic values. Block 0's thread t polls blocks t and
// t+256; releases via per-block private lines.
__device__ __forceinline__ void grid_barrier5(unsigned* arr, unsigned* rel,
                                              int s) {
  asm volatile("s_waitcnt vmcnt(0)" ::: "memory");
  __syncthreads();
  const unsigned v = (unsigned)s + 1u;
  const int bid = blockIdx.x, tid = threadIdx.x;
  if (bid == 0) {
    if (tid > 0) {
      while (__hip_atomic_load(&arr[(unsigned)tid * 32u], __ATOMIC_RELAXED,
                               __HIP_MEMORY_SCOPE_AGENT) < v)
        __builtin_amdgcn_s_sleep(1);
    }
    while (__hip_atomic_load(&arr[((unsigned)tid + 256u) * 32u],
                             __ATOMIC_RELAXED, __HIP_MEMORY_SCOPE_AGENT) < v)
      __builtin_amdgcn_s_sleep(1);
    __syncthreads();  // all 511 arrivals observed
    if (tid > 0)
      __hip_atomic_store(&rel[(unsigned)tid * 32u], v, __ATOMIC_RELAXED,
                         __HIP_MEMORY_SCOPE_AGENT);
    __hip_atomic_store(&rel[((unsigned)tid + 256u) * 32u], v, __ATOMIC_RELAXED,
                       __HIP_MEMORY_SCOPE_AGENT);
  } else {
    if (tid == 0) {
      __hip_atomic_store(&arr[(unsigned)bid * 32u], v, __ATOMIC_RELAXED,
                         __HIP_MEMORY_SCOPE_AGENT);
      while (__hip_atomic_load(&rel[(unsigned)bid * 32u], __ATOMIC_RELAXED,
                               __HIP_MEMORY_SCOPE_AGENT) < v)
        __builtin_amdgcn_s_sleep(1);
    }
    __syncthreads();
  }
}

// ---------- shared epilogue piece: 4-wave partial reduce through LDS ----------
// z[g] must be pre-seeded with xz or bias by the caller.
__device__ __forceinline__ void reduce4(const f32x4 acc[4], float* zred,
                                        float z[4]) {
  const int tid = threadIdx.x, lane = tid & 63, w = tid >> 6;
  const int j = lane & 15, kg = lane >> 4;
#pragma unroll
  for (int mf = 0; mf < 4; ++mf)
#pragma unroll
    for (int r = 0; r < 4; ++r)
      zred[w * 1088 + (mf * 16 + kg * 4 + r) * 17 + j] = acc[mf][r];
  __syncthreads();
  const int erow = tid >> 2, euu = tid & 3;
#pragma unroll
  for (int g = 0; g < 4; ++g) {
#pragma unroll
    for (int wv = 0; wv < 4; ++wv)
      z[g] += zred[wv * 1088 + erow * 17 + g * 4 + euu];
  }
}

// ---------- role-split persistent scan ----------
// bid<256: layer 0, units [4b,4b+4): h0(s) = LSTM0(xz(s), h0(s-1)).
// bid>=256: layer 1: h1(t=s-1) = LSTM1(h0(t)@W1 + h1(t-1)@U1 + b1).
// All h stores write-through to write-once slots A1[s] / H1h[t].
__global__ __launch_bounds__(256, 2) void k_scan2(
    const f16* __restrict__ XZ, const f16* __restrict__ U0t,
    const f16* __restrict__ W1t, const f16* __restrict__ U1t,
    const float* __restrict__ b1, f16* __restrict__ A1,
    f16* __restrict__ H1h, float* __restrict__ out, unsigned* arr,
    unsigned* rel) {
  __shared__ float zred[4352];
  const int tid = threadIdx.x, lane = tid & 63, w = tid >> 6;
  const bool isL1 = (blockIdx.x >= 256);
  const int bm = isL1 ? (int)blockIdx.x - 256 : (int)blockIdx.x;
  const int u0 = bm * 4;
  const int j = lane & 15, kg = lane >> 4;
  const int ncol = (j >> 2) * 1024 + u0 + (j & 3);
  const int woff = ncol * 1024 + w * 256 + kg * 8;
  const int aoff = j * 1024 + w * 256 + kg * 8;
  const int erow = tid >> 2, euu = tid & 3, eu = u0 + euu;

  // role weights in registers for the whole scan
  f16x8 bvA[8], bvB[8];
#pragma unroll
  for (int kt = 0; kt < 8; ++kt)
    bvA[kt] = *(const f16x8*)((isL1 ? W1t : U0t) + woff + kt * 32);
  if (isL1) {
#pragma unroll
    for (int kt = 0; kt < 8; ++kt)
      bvB[kt] = *(const f16x8*)(U1t + woff + kt * 32);
  }
  float bias1[4] = {0.f, 0.f, 0.f, 0.f};
  if (isL1) {
#pragma unroll
    for (int g = 0; g < 4; ++g) bias1[g] = b1[g * 1024 + eu];
  }
  float c = 0.0f;  // this role's cell state, in a register
  float xz[4] = {0.f, 0.f, 0.f, 0.f};
  if (!isL1) {
#pragma unroll
    for (int g = 0; g < 4; ++g)
      xz[g] = (float)XZ[(size_t)erow * 4096 + g * 1024 + eu];
  }

  for (int s = 0; s <= 256; ++s) {
    if (!isL1) {
      if (s < 256) {
        f32x4 acc[4] = {};
        if (s > 0) {
          const f16* ap = A1 + (size_t)(s - 1) * 65536 + aoff;
#pragma unroll
          for (int kt = 0; kt < 8; ++kt)
#pragma unroll
            for (int mf = 0; mf < 4; ++mf)
              acc[mf] = mfma16x32(*(const f16x8*)(ap + mf * 16384 + kt * 32),
                                  bvA[kt], acc[mf]);
        }
        float z[4] = {xz[0], xz[1], xz[2], xz[3]};
        reduce4(acc, zred, z);
        float gi = sigmoidf_(z[0]), gf = sigmoidf_(z[1]);
        float gg = tanhf(z[2]), go = sigmoidf_(z[3]);
        c = gf * c + gi * gg;
        st_f16_sc(&A1[(size_t)(s * 64 + erow) * 1024 + eu], go * tanhf(c));
      }
    } else {
      if (s >= 1) {
        const int t = s - 1;
        f32x4 acc[4] = {};
        const f16* ap = A1 + (size_t)t * 65536 + aoff;  // h0(t)
#pragma unroll
        for (int kt = 0; kt < 8; ++kt)
#pragma unroll
          for (int mf = 0; mf < 4; ++mf)
            acc[mf] = mfma16x32(*(const f16x8*)(ap + mf * 16384 + kt * 32),
                                bvA[kt], acc[mf]);
        if (t > 0) {
          const f16* hp = H1h + (size_t)(t - 1) * 65536 + aoff;  // h1(t-1)
#pragma unroll
          for (int kt = 0; kt < 8; ++kt)
#pragma unroll
            for (int mf = 0; mf < 4; ++mf)
              acc[mf] = mfma16x32(*(const f16x8*)(hp + mf * 16384 + kt * 32),
                                  bvB[kt], acc[mf]);
        }
        float z[4] = {bias1[0], bias1[1], bias1[2], bias1[3]};
        reduce4(acc, zred, z);
        float gi = sigmoidf_(z[0]), gf = sigmoidf_(z[1]);
        float gg = tanhf(z[2]), go = sigmoidf_(z[3]);
        c = gf * c + gi * gg;
        float hn = go * tanhf(c);
        st_f16_sc(&H1h[(size_t)t * 65536 + erow * 1024 + eu], hn);
        out[(size_t)erow * 262144 + (size_t)t * 1024 + eu] = hn;
        if (t == 255) {
          out[16777216 + erow * 1024 + eu] = hn;
          out[16777216 + 65536 + erow * 1024 + eu] = c;
        }
      }
    }
    // prefetch next step's xz; completes long before the barrier releases
    float xzn[4] = {0.f, 0.f, 0.f, 0.f};
    if (!isL1 && s + 1 < 256) {
      const f16* xrow = XZ + (size_t)((s + 1) * 64 + erow) * 4096;
#pragma unroll
      for (int g = 0; g < 4; ++g) xzn[g] = (float)xrow[g * 1024 + eu];
    }
    if (s < 256) grid_barrier5(arr, rel, s);
    if (!isL1) {
#pragma unroll
      for (int g = 0; g < 4; ++g) xz[g] = xzn[g];
    }
  }
}

// ---------- fallback: fused per-step kernel (proven in r6) ----------
__device__ __forceinline__ void step_once(
    int s, int u0, const f16x8 bvU0[8], const f16x8 bvW1[8],
    const f16x8 bvU1[8], const float bias1[4], const float xz[4],
    f16* __restrict__ A1, f16* __restrict__ H1h, int hmask,
    float& c0, float& c1, float* __restrict__ out, float* zred) {
  const int tid = threadIdx.x, lane = tid & 63, w = tid >> 6;
  const int j = lane & 15, kg = lane >> 4;
  const int aoff = j * 1024 + w * 256 + kg * 8;
  const int erow = tid >> 2, euu = tid & 3;
  const int eu = u0 + euu;

  f32x4 accA[4] = {};
  f32x4 accB[4] = {};

  if (s >= 1) {
    const f16* ap = A1 + (size_t)(s - 1) * 65536 + aoff;
#pragma unroll
    for (int kt = 0; kt < 8; ++kt)
#pragma unroll
      for (int mf = 0; mf < 4; ++mf) {
        f16x8 av = *(const f16x8*)(ap + mf * 16384 + kt * 32);
        if (s < 256) accA[mf] = mfma16x32(av, bvU0[kt], accA[mf]);
        accB[mf] = mfma16x32(av, bvW1[kt], accB[mf]);
      }
    if (s >= 2) {
      const f16* hp = H1h + (size_t)((s - 2) & hmask) * 65536 + aoff;
#pragma unroll
      for (int kt = 0; kt < 8; ++kt)
#pragma unroll
        for (int mf = 0; mf < 4; ++mf)
          accB[mf] = mfma16x32(*(const f16x8*)(hp + mf * 16384 + kt * 32),
                               bvU1[kt], accB[mf]);
    }
  }

  if (s < 256) {
    float z[4] = {xz[0], xz[1], xz[2], xz[3]};
    reduce4(accA, zred, z);
    float gi = sigmoidf_(z[0]), gf = sigmoidf_(z[1]);
    float gg = tanhf(z[2]), go = sigmoidf_(z[3]);
    c0 = gf * c0 + gi * gg;
    st_f16_sc(&A1[(size_t)(s * 64 + erow) * 1024 + eu], go * tanhf(c0));
  }
  __syncthreads();

  if (s >= 1) {
    const int t = s - 1;
    float z[4] = {bias1[0], bias1[1], bias1[2], bias1[3]};
    reduce4(accB, zred, z);
    float gi = sigmoidf_(z[0]), gf = sigmoidf_(z[1]);
    float gg = tanhf(z[2]), go = sigmoidf_(z[3]);
    c1 = gf * c1 + gi * gg;
    float hn = go * tanhf(c1);
    st_f16_sc(&H1h[(size_t)(t & hmask) * 65536 + erow * 1024 + eu], hn);
    out[(size_t)erow * 262144 + (size_t)t * 1024 + eu] = hn;
    if (t == 255) {
      out[16777216 + erow * 1024 + eu] = hn;
      out[16777216 + 65536 + erow * 1024 + eu] = c1;
    }
  }
}

__global__ __launch_bounds__(256, 1) void k_step(
    const f16* __restrict__ XZ, const f16* __restrict__ U0t,
    const f16* __restrict__ W1t, const f16* __restrict__ U1t,
    const float* __restrict__ b1, f16* __restrict__ A1,
    f16* __restrict__ H1h, float* __restrict__ C0, float* __restrict__ C1,
    float* __restrict__ out, int s) {
  __shared__ float zred[4352];
  const int tid_ = threadIdx.x, lane_ = tid_ & 63, w_ = tid_ >> 6;
  const int u0 = blockIdx.x * 4;
  const int j_ = lane_ & 15;
  const int kg_ = lane_ >> 4;
  const int ncol_ = (j_ >> 2) * 1024 + u0 + (j_ & 3);
  const int woff_ = ncol_ * 1024 + w_ * 256 + kg_ * 8;
  f16x8 bvU0[8], bvW1[8], bvU1[8];
#pragma unroll
  for (int kt = 0; kt < 8; ++kt) {
    bvU0[kt] = *(const f16x8*)(U0t + woff_ + kt * 32);
    bvW1[kt] = *(const f16x8*)(W1t + woff_ + kt * 32);
    bvU1[kt] = *(const f16x8*)(U1t + woff_ + kt * 32);
  }
  const int erow_ = tid_ >> 2;
  const int eu_ = u0 + (tid_ & 3);
  float bias1[4];
#pragma unroll
  for (int g = 0; g < 4; ++g) bias1[g] = b1[g * 1024 + eu_];

  float xz[4] = {0.f, 0.f, 0.f, 0.f};
  if (s < 256) {
    const f16* xrow = XZ + (size_t)(s * 64 + erow_) * 4096;
#pragma unroll
    for (int g = 0; g < 4; ++g) xz[g] = (float)xrow[g * 1024 + eu_];
  }
  float c0 = C0[erow_ * 1024 + eu_];
  float c1 = C1[erow_ * 1024 + eu_];
  step_once(s, u0, bvU0, bvW1, bvU1, bias1, xz, A1, H1h, 1, c0, c1, out,
            zred);
  C0[erow_ * 1024 + eu_] = c0;
  C1[erow_ * 1024 + eu_] = c1;
}

extern "C" void kernel_launch(void* const* d_in, const int* in_sizes, int n_in,
                              void* d_out, int out_size, void* d_ws, size_t ws_size,
                              hipStream_t stream) {
  (void)in_sizes; (void)n_in; (void)out_size;
  const int* tokens = (const int*)d_in[0];
  const float* emb = (const float*)d_in[1];
  const float* W0 = (const float*)d_in[2];
  const float* U0 = (const float*)d_in[3];
  const float* b0 = (const float*)d_in[4];
  const float* W1 = (const float*)d_in[5];
  const float* U1 = (const float*)d_in[6];
  const float* b1 = (const float*)d_in[7];
  float* out = (float*)d_out;

  // workspace carve-up; H1h LAST (coop path needs the full 256 slots)
  char* p = (char*)d_ws;
  f16* A0 = (f16*)p;   p += (size_t)16384 * 512 * 2;    // x tokens, fp16
  f16* A1 = (f16*)p;   p += (size_t)16384 * 1024 * 2;   // h0 history
  f16* W0t = (f16*)p;  p += (size_t)4096 * 512 * 2;     // W0^T
  f16* U0t = (f16*)p;  p += (size_t)4096 * 1024 * 2;    // U0^T
  f16* W1t = (f16*)p;  p += (size_t)4096 * 1024 * 2;    // W1^T
  f16* U1t = (f16*)p;  p += (size_t)4096 * 1024 * 2;    // U1^T
  f16* XZ = (f16*)p;   p += (size_t)16384 * 4096 * 2;   // xz0, rows t*64+b
  float* C0 = (float*)p; p += 64 * 1024 * 4;            // cell L0 (fallback)
  float* C1 = (float*)p; p += 64 * 1024 * 4;            // cell L1 (fallback)
  unsigned* arr = (unsigned*)p; p += 512 * 32 * 4;      // arrive lines
  unsigned* rel = (unsigned*)p; p += 512 * 32 * 4;      // release lines
  f16* H1h = (f16*)p;                                   // h1 history slots
  const size_t need_coop = (size_t)(p - (char*)d_ws) + (size_t)256 * 65536 * 2;

  // weight transposes + casts
  k_transpose_f16<<<512, 256, 0, stream>>>(W0, W0t, 512, 4096);
  k_transpose_f16<<<1024, 256, 0, stream>>>(U0, U0t, 1024, 4096);
  k_transpose_f16<<<1024, 256, 0, stream>>>(W1, W1t, 1024, 4096);
  k_transpose_f16<<<1024, 256, 0, stream>>>(U1, U1t, 1024, 4096);

  // embedding
  k_embed_f16<<<8192, 256, 0, stream>>>(tokens, emb, A0);

  // layer 0 input projection: xz0 = x @ W0 + b0
  k_gemm_f16<<<4096, 256, 0, stream>>>(A0, W0t, b0, XZ, 16384, 4096, 512);

  hipMemsetAsync(C0, 0, 64 * 1024 * 4 * 2, stream);  // C0+C1
  hipMemsetAsync(arr, 0, 512 * 32 * 4 * 2, stream);  // arr+rel

  bool coop_ok = (ws_size >= need_coop);
  if (coop_ok) {
    const f16* XZc = XZ; const f16* U0c = U0t; const f16* W1c = W1t;
    const f16* U1c = U1t; const float* b1c = b1;
    f16* A1p = A1; f16* H1p = H1h; float* outp = out;
    unsigned* ar = arr; unsigned* rl = rel;
    void* kargs[] = {(void*)&XZc, (void*)&U0c, (void*)&W1c, (void*)&U1c,
                     (void*)&b1c, (void*)&A1p, (void*)&H1p, (void*)&outp,
                     (void*)&ar, (void*)&rl};
    hipError_t e = hipLaunchCooperativeKernel((const void*)k_scan2, dim3(512),
                                              dim3(256), kargs, 0, stream);
    if (e != hipSuccess) {
      (void)hipGetLastError();
      coop_ok = false;
    }
  }
  if (!coop_ok) {
    for (int s = 0; s <= 256; ++s)
      k_step<<<256, 256, 0, stream>>>(XZ, U0t, W1t, U1t, b1, A1, H1h, C0, C1,
                                      out, s);
  }
}

// Round 8
// 3656.953 us; speedup vs baseline: 5.5253x; 1.0337x over previous
//
#include <hip/hip_runtime.h>

// LSTM encoder: V=32000 E=512 U=1024 L=2, B=64 T=256.
// Round 8: decoupled dataflow scan. Two independent 256-block barriers
// (L0 blocks 0-255, L1 blocks 256-511); L0 publishes an epoch that gates
// L1's reads of A1 (mirror lines, 1-writer/1-reader); L1 hides its W1-pass
// (load A1[t+1] + 32 MFMA) under its own barrier wait. Round 7 lock-stepped
// both layers through one 512-block barrier at 14.8us/step.

typedef _Float16 f16;
typedef _Float16 f16x8 __attribute__((ext_vector_type(8)));
typedef _Float16 f16x4 __attribute__((ext_vector_type(4)));
typedef float f32x4 __attribute__((ext_vector_type(4)));

__device__ __forceinline__ f32x4 mfma16x32(f16x8 a, f16x8 b, f32x4 c) {
  return __builtin_amdgcn_mfma_f32_16x16x32_f16(a, b, c, 0, 0, 0);
}

__device__ __forceinline__ void gl_lds16(const void* g, void* l) {
  __builtin_amdgcn_global_load_lds(
      (const __attribute__((address_space(1))) void*)g,
      (__attribute__((address_space(3))) void*)l, 16, 0, 0);
}

__device__ __forceinline__ float sigmoidf_(float x) {
  return 1.0f / (1.0f + expf(-x));
}

// write-through f16 store: lands at the L3 coherence point, no dirty L2 line
__device__ __forceinline__ void st_f16_sc(f16* p, float v) {
  f16 h = (f16)v;
  unsigned u = (unsigned)__builtin_bit_cast(unsigned short, h);
  asm volatile("global_store_short %0, %1, off sc0 sc1"
               :: "v"(p), "v"(u) : "memory");
}

__device__ __forceinline__ unsigned ld_flag(const unsigned* p) {
  return __hip_atomic_load(p, __ATOMIC_RELAXED, __HIP_MEMORY_SCOPE_AGENT);
}
__device__ __forceinline__ void st_flag(unsigned* p, unsigned v) {
  __hip_atomic_store(p, v, __ATOMIC_RELAXED, __HIP_MEMORY_SCOPE_AGENT);
}

// ---------- transpose + cast: D[n][k] = (f16)S[k][n] ----------
__global__ __launch_bounds__(256) void k_transpose_f16(
    const float* __restrict__ S, f16* __restrict__ D, int K, int N) {
  __shared__ float tile[64][65];
  int nk = K >> 6;
  int k0 = (blockIdx.x % nk) << 6;
  int n0 = (blockIdx.x / nk) << 6;
  int tc = threadIdx.x & 63;
  int tq = threadIdx.x >> 6;
#pragma unroll
  for (int r = 0; r < 16; ++r) {
    int kk = tq * 16 + r;
    tile[kk][tc] = S[(size_t)(k0 + kk) * N + (n0 + tc)];
  }
  __syncthreads();
#pragma unroll
  for (int r = 0; r < 16; ++r) {
    int nn = tq * 16 + r;
    D[(size_t)(n0 + nn) * K + (k0 + tc)] = (f16)tile[tc][nn];
  }
}

// ---------- embedding lookup -> fp16 A0[m][512], row m = t*64 + b ----------
__global__ __launch_bounds__(256) void k_embed_f16(
    const int* __restrict__ tok, const float* __restrict__ emb,
    f16* __restrict__ A0) {
  int i = blockIdx.x * 256 + threadIdx.x;
  int m = i >> 7;
  int e = (i & 127) << 2;
  int t = m >> 6, b = m & 63;
  int tk = tok[b * 256 + t];
  const float4 v = *(const float4*)(emb + (size_t)tk * 512 + e);
  f16x4 o = {(f16)v.x, (f16)v.y, (f16)v.z, (f16)v.w};
  *(f16x4*)(A0 + (size_t)m * 512 + e) = o;
}

// ---------- C[m][n] = (f16)(sum_k A[m][k]*Bt[n][k] + bias[n]) ----------
__global__ __launch_bounds__(256) void k_gemm_f16(
    const f16* __restrict__ A, const f16* __restrict__ Bt,
    const float* __restrict__ bias, f16* __restrict__ C,
    int M, int N, int K) {
  __shared__ f16 sA[2][128 * 32];
  __shared__ f16 sB[2][128 * 32];
  const int tid = threadIdx.x, lane = tid & 63, w = tid >> 6;
  const int mb = M >> 7;
  const int bm = blockIdx.x % mb, bn = blockIdx.x / mb;
  const int am0 = bm << 7, bn0 = bn << 7;
  const int wm = w >> 1, wn = w & 1;
  const int srow = lane >> 2, sch = lane & 3;

  f32x4 acc[4][4] = {};
  const int NT = K >> 5;
  int cur = 0;

  auto stage = [&](int kt, int buf) {
#pragma unroll
    for (int q2 = 0; q2 < 2; ++q2) {
      int q = w * 2 + q2;
      int row = q * 16 + srow;
      const f16* ga = A + (size_t)(am0 + row) * K + kt * 32 + sch * 8;
      const f16* gb = Bt + (size_t)(bn0 + row) * K + kt * 32 + sch * 8;
      gl_lds16(ga, (char*)&sA[buf][0] + q * 1024);
      gl_lds16(gb, (char*)&sB[buf][0] + q * 1024);
    }
  };

  stage(0, 0);
  __syncthreads();
  for (int kt = 0; kt < NT; ++kt) {
    if (kt + 1 < NT) stage(kt + 1, cur ^ 1);
    const f16* pa = &sA[cur][(wm * 64 + (lane & 15)) * 32 + (lane >> 4) * 8];
    const f16* pb = &sB[cur][(wn * 64 + (lane & 15)) * 32 + (lane >> 4) * 8];
    f16x8 av[4], bv[4];
#pragma unroll
    for (int mf = 0; mf < 4; ++mf) av[mf] = *(const f16x8*)(pa + mf * 512);
#pragma unroll
    for (int nf = 0; nf < 4; ++nf) bv[nf] = *(const f16x8*)(pb + nf * 512);
#pragma unroll
    for (int mf = 0; mf < 4; ++mf)
#pragma unroll
      for (int nf = 0; nf < 4; ++nf)
        acc[mf][nf] = mfma16x32(av[mf], bv[nf], acc[mf][nf]);
    __syncthreads();
    cur ^= 1;
  }

#pragma unroll
  for (int mf = 0; mf < 4; ++mf)
#pragma unroll
    for (int nf = 0; nf < 4; ++nf) {
      int col = bn0 + wn * 64 + nf * 16 + (lane & 15);
      float bs = bias[col];
#pragma unroll
      for (int r = 0; r < 4; ++r) {
        int row = am0 + wm * 64 + mf * 16 + (lane >> 4) * 4 + r;
        C[(size_t)row * N + col] = (f16)(acc[mf][nf][r] + bs);
      }
    }
}

// ---------- shared epilogue piece: 4-wave partial reduce through LDS ----------
__device__ __forceinline__ void reduce4(const f32x4 acc[4], float* zred,
                                        float z[4]) {
  const int tid = threadIdx.x, lane = tid & 63, w = tid >> 6;
  const int j = lane & 15, kg = lane >> 4;
#pragma unroll
  for (int mf = 0; mf < 4; ++mf)
#pragma unroll
    for (int r = 0; r < 4; ++r)
      zred[w * 1088 + (mf * 16 + kg * 4 + r) * 17 + j] = acc[mf][r];
  __syncthreads();
  const int erow = tid >> 2, euu = tid & 3;
#pragma unroll
  for (int g = 0; g < 4; ++g) {
#pragma unroll
    for (int wv = 0; wv < 4; ++wv)
      z[g] += zred[wv * 1088 + erow * 17 + g * 4 + euu];
  }
}

// ---------- decoupled persistent scan ----------
// Blocks 0-255 (L0): h0(s) = LSTM0(xz(s) + U0 h0(s-1)); own barrier; leader
// (block 0) publishes epoch s+1 to per-L1-block mirror lines after gather.
// Blocks 256-511 (L1): h1(t) = LSTM1(W1 h0(t) + U1 h1(t-1) + b1); own
// barrier; the W1 pass for step t+1 runs in the barrier-wait window, gated
// on mir >= t+2. All cross-block h stores are sc0/sc1 write-through to
// write-once slots (fence-free visibility, proven r6/r7).
__global__ __launch_bounds__(256, 2) void k_scan3(
    const f16* __restrict__ XZ, const f16* __restrict__ U0t,
    const f16* __restrict__ W1t, const f16* __restrict__ U1t,
    const float* __restrict__ b1, f16* __restrict__ A1,
    f16* __restrict__ H1h, float* __restrict__ out, unsigned* arr0,
    unsigned* rel0, unsigned* arr1, unsigned* rel1, unsigned* mir) {
  __shared__ float zred[4352];
  const int tid = threadIdx.x, lane = tid & 63, w = tid >> 6;
  const bool isL1 = (blockIdx.x >= 256);
  const int i = isL1 ? (int)blockIdx.x - 256 : (int)blockIdx.x;
  const int u0 = i * 4;
  const int j = lane & 15, kg = lane >> 4;
  const int ncol = (j >> 2) * 1024 + u0 + (j & 3);
  const int woff = ncol * 1024 + w * 256 + kg * 8;
  const int aoff = j * 1024 + w * 256 + kg * 8;
  const int erow = tid >> 2, eu = u0 + (tid & 3);

  f16x8 bvA[8], bvB[8];
#pragma unroll
  for (int kt = 0; kt < 8; ++kt)
    bvA[kt] = *(const f16x8*)((isL1 ? W1t : U0t) + woff + kt * 32);
  if (isL1) {
#pragma unroll
    for (int kt = 0; kt < 8; ++kt)
      bvB[kt] = *(const f16x8*)(U1t + woff + kt * 32);
  }
  float c = 0.0f;

  if (!isL1) {
    // ================= layer 0 =================
    float xz[4];
#pragma unroll
    for (int g = 0; g < 4; ++g)
      xz[g] = (float)XZ[(size_t)erow * 4096 + g * 1024 + eu];

    for (int s = 0; s < 256; ++s) {
      f32x4 acc[4] = {};
      if (s > 0) {
        const f16* ap = A1 + (size_t)(s - 1) * 65536 + aoff;
#pragma unroll
        for (int kt = 0; kt < 8; ++kt)
#pragma unroll
          for (int mf = 0; mf < 4; ++mf)
            acc[mf] = mfma16x32(*(const f16x8*)(ap + mf * 16384 + kt * 32),
                                bvA[kt], acc[mf]);
      }
      float z[4] = {xz[0], xz[1], xz[2], xz[3]};
      reduce4(acc, zred, z);
      float gi = sigmoidf_(z[0]), gf = sigmoidf_(z[1]);
      float gg = tanhf(z[2]), go = sigmoidf_(z[3]);
      c = gf * c + gi * gg;
      st_f16_sc(&A1[(size_t)(s * 64 + erow) * 1024 + eu], go * tanhf(c));

      // prefetch next xz; drained together with the publish below
      float xzn[4] = {0.f, 0.f, 0.f, 0.f};
      if (s + 1 < 256) {
        const f16* xrow = XZ + (size_t)((s + 1) * 64 + erow) * 4096;
#pragma unroll
        for (int g = 0; g < 4; ++g) xzn[g] = (float)xrow[g * 1024 + eu];
      }

      // barrier0(s): after it completes, epoch = s+1 (A1[0..s] visible)
      asm volatile("s_waitcnt vmcnt(0)" ::: "memory");
      __syncthreads();
      const unsigned v = (unsigned)s + 1u;
      if (i == 0) {
        if (tid > 0) {
          while (ld_flag(&arr0[(unsigned)tid * 32u]) < v)
            __builtin_amdgcn_s_sleep(1);
        }
        __syncthreads();  // all 255 arrivals observed
        if (tid > 0) st_flag(&rel0[(unsigned)tid * 32u], v);
        st_flag(&mir[(unsigned)tid * 32u], v);  // epoch to every L1 block
      } else {
        if (tid == 0) {
          st_flag(&arr0[(unsigned)i * 32u], v);
          while (ld_flag(&rel0[(unsigned)i * 32u]) < v)
            __builtin_amdgcn_s_sleep(1);
        }
        __syncthreads();
      }
#pragma unroll
      for (int g = 0; g < 4; ++g) xz[g] = xzn[g];
    }
  } else {
    // ================= layer 1 =================
    float bias1[4];
#pragma unroll
    for (int g = 0; g < 4; ++g) bias1[g] = b1[g * 1024 + eu];

    // prime: wait epoch 1, compute accW = W1 * h0(0)
    if (tid == 0) {
      while (ld_flag(&mir[(unsigned)i * 32u]) < 1u)
        __builtin_amdgcn_s_sleep(1);
    }
    __syncthreads();
    f32x4 accW[4] = {};
    {
      const f16* ap = A1 + aoff;
#pragma unroll
      for (int kt = 0; kt < 8; ++kt)
#pragma unroll
        for (int mf = 0; mf < 4; ++mf)
          accW[mf] = mfma16x32(*(const f16x8*)(ap + mf * 16384 + kt * 32),
                               bvA[kt], accW[mf]);
    }

    for (int t = 0; t < 256; ++t) {
      f32x4 acc[4] = {accW[0], accW[1], accW[2], accW[3]};
      if (t > 0) {
        const f16* hp = H1h + (size_t)(t - 1) * 65536 + aoff;
#pragma unroll
        for (int kt = 0; kt < 8; ++kt)
#pragma unroll
          for (int mf = 0; mf < 4; ++mf)
            acc[mf] = mfma16x32(*(const f16x8*)(hp + mf * 16384 + kt * 32),
                                bvB[kt], acc[mf]);
      }
      float z[4] = {bias1[0], bias1[1], bias1[2], bias1[3]};
      reduce4(acc, zred, z);
      float gi = sigmoidf_(z[0]), gf = sigmoidf_(z[1]);
      float gg = tanhf(z[2]), go = sigmoidf_(z[3]);
      c = gf * c + gi * gg;
      float hn = go * tanhf(c);
      out[(size_t)erow * 262144 + (size_t)t * 1024 + eu] = hn;
      if (t == 255) {
        out[16777216 + erow * 1024 + eu] = hn;
        out[16777216 + 65536 + erow * 1024 + eu] = c;
        break;  // last step: no publish/barrier needed
      }
      st_f16_sc(&H1h[(size_t)t * 65536 + erow * 1024 + eu], hn);

      // barrier1(t) with W1-pass overlap in the wait window
      asm volatile("s_waitcnt vmcnt(0)" ::: "memory");
      __syncthreads();
      const unsigned v = (unsigned)t + 1u;
      if (i == 0) {
        // leader: gather + release FIRST so workers aren't held up
        if (tid > 0) {
          while (ld_flag(&arr1[(unsigned)tid * 32u]) < v)
            __builtin_amdgcn_s_sleep(1);
        }
        __syncthreads();
        if (tid > 0) st_flag(&rel1[(unsigned)tid * 32u], v);
      } else {
        if (tid == 0) st_flag(&arr1[(unsigned)i * 32u], v);
      }
      // overlap: next step's W1 pass, gated on epoch t+2
      if (tid == 0) {
        while (ld_flag(&mir[(unsigned)i * 32u]) < v + 1u)
          __builtin_amdgcn_s_sleep(1);
      }
      __syncthreads();
      {
        const f16* ap = A1 + (size_t)(t + 1) * 65536 + aoff;
#pragma unroll
        for (int mf = 0; mf < 4; ++mf) acc[mf] = f32x4{0.f, 0.f, 0.f, 0.f};
#pragma unroll
        for (int kt = 0; kt < 8; ++kt)
#pragma unroll
          for (int mf = 0; mf < 4; ++mf)
            acc[mf] = mfma16x32(*(const f16x8*)(ap + mf * 16384 + kt * 32),
                                bvA[kt], acc[mf]);
#pragma unroll
        for (int mf = 0; mf < 4; ++mf) accW[mf] = acc[mf];
      }
      // wait for release (workers; leader already released)
      if (i != 0) {
        if (tid == 0) {
          while (ld_flag(&rel1[(unsigned)i * 32u]) < v)
            __builtin_amdgcn_s_sleep(1);
        }
        __syncthreads();
      }
    }
  }
}

// ---------- fallback: fused per-step kernel (proven r6/r7) ----------
__device__ __forceinline__ void step_once(
    int s, int u0, const f16x8 bvU0[8], const f16x8 bvW1[8],
    const f16x8 bvU1[8], const float bias1[4], const float xz[4],
    f16* __restrict__ A1, f16* __restrict__ H1h, int hmask,
    float& c0, float& c1, float* __restrict__ out, float* zred) {
  const int tid = threadIdx.x, lane = tid & 63, w = tid >> 6;
  const int j = lane & 15, kg = lane >> 4;
  const int aoff = j * 1024 + w * 256 + kg * 8;
  const int erow = tid >> 2;
  const int eu = u0 + (tid & 3);

  f32x4 accA[4] = {};
  f32x4 accB[4] = {};

  if (s >= 1) {
    const f16* ap = A1 + (size_t)(s - 1) * 65536 + aoff;
#pragma unroll
    for (int kt = 0; kt < 8; ++kt)
#pragma unroll
      for (int mf = 0; mf < 4; ++mf) {
        f16x8 av = *(const f16x8*)(ap + mf * 16384 + kt * 32);
        if (s < 256) accA[mf] = mfma16x32(av, bvU0[kt], accA[mf]);
        accB[mf] = mfma16x32(av, bvW1[kt], accB[mf]);
      }
    if (s >= 2) {
      const f16* hp = H1h + (size_t)((s - 2) & hmask) * 65536 + aoff;
#pragma unroll
      for (int kt = 0; kt < 8; ++kt)
#pragma unroll
        for (int mf = 0; mf < 4; ++mf)
          accB[mf] = mfma16x32(*(const f16x8*)(hp + mf * 16384 + kt * 32),
                               bvU1[kt], accB[mf]);
    }
  }

  if (s < 256) {
    float z[4] = {xz[0], xz[1], xz[2], xz[3]};
    reduce4(accA, zred, z);
    float gi = sigmoidf_(z[0]), gf = sigmoidf_(z[1]);
    float gg = tanhf(z[2]), go = sigmoidf_(z[3]);
    c0 = gf * c0 + gi * gg;
    st_f16_sc(&A1[(size_t)(s * 64 + erow) * 1024 + eu], go * tanhf(c0));
  }
  __syncthreads();

  if (s >= 1) {
    const int t = s - 1;
    float z[4] = {bias1[0], bias1[1], bias1[2], bias1[3]};
    reduce4(accB, zred, z);
    float gi = sigmoidf_(z[0]), gf = sigmoidf_(z[1]);
    float gg = tanhf(z[2]), go = sigmoidf_(z[3]);
    c1 = gf * c1 + gi * gg;
    float hn = go * tanhf(c1);
    st_f16_sc(&H1h[(size_t)(t & hmask) * 65536 + erow * 1024 + eu], hn);
    out[(size_t)erow * 262144 + (size_t)t * 1024 + eu] = hn;
    if (t == 255) {
      out[16777216 + erow * 1024 + eu] = hn;
      out[16777216 + 65536 + erow * 1024 + eu] = c1;
    }
  }
}

__global__ __launch_bounds__(256, 1) void k_step(
    const f16* __restrict__ XZ, const f16* __restrict__ U0t,
    const f16* __restrict__ W1t, const f16* __restrict__ U1t,
    const float* __restrict__ b1, f16* __restrict__ A1,
    f16* __restrict__ H1h, float* __restrict__ C0, float* __restrict__ C1,
    float* __restrict__ out, int s) {
  __shared__ float zred[4352];
  const int tid_ = threadIdx.x, lane_ = tid_ & 63, w_ = tid_ >> 6;
  const int u0 = blockIdx.x * 4;
  const int j_ = lane_ & 15;
  const int kg_ = lane_ >> 4;
  const int ncol_ = (j_ >> 2) * 1024 + u0 + (j_ & 3);
  const int woff_ = ncol_ * 1024 + w_ * 256 + kg_ * 8;
  f16x8 bvU0[8], bvW1[8], bvU1[8];
#pragma unroll
  for (int kt = 0; kt < 8; ++kt) {
    bvU0[kt] = *(const f16x8*)(U0t + woff_ + kt * 32);
    bvW1[kt] = *(const f16x8*)(W1t + woff_ + kt * 32);
    bvU1[kt] = *(const f16x8*)(U1t + woff_ + kt * 32);
  }
  const int erow_ = tid_ >> 2;
  const int eu_ = u0 + (tid_ & 3);
  float bias1[4];
#pragma unroll
  for (int g = 0; g < 4; ++g) bias1[g] = b1[g * 1024 + eu_];

  float xz[4] = {0.f, 0.f, 0.f, 0.f};
  if (s < 256) {
    const f16* xrow = XZ + (size_t)(s * 64 + erow_) * 4096;
#pragma unroll
    for (int g = 0; g < 4; ++g) xz[g] = (float)xrow[g * 1024 + eu_];
  }
  float c0 = C0[erow_ * 1024 + eu_];
  float c1 = C1[erow_ * 1024 + eu_];
  step_once(s, u0, bvU0, bvW1, bvU1, bias1, xz, A1, H1h, 1, c0, c1, out,
            zred);
  C0[erow_ * 1024 + eu_] = c0;
  C1[erow_ * 1024 + eu_] = c1;
}

extern "C" void kernel_launch(void* const* d_in, const int* in_sizes, int n_in,
                              void* d_out, int out_size, void* d_ws, size_t ws_size,
                              hipStream_t stream) {
  (void)in_sizes; (void)n_in; (void)out_size;
  const int* tokens = (const int*)d_in[0];
  const float* emb = (const float*)d_in[1];
  const float* W0 = (const float*)d_in[2];
  const float* U0 = (const float*)d_in[3];
  const float* b0 = (const float*)d_in[4];
  const float* W1 = (const float*)d_in[5];
  const float* U1 = (const float*)d_in[6];
  const float* b1 = (const float*)d_in[7];
  float* out = (float*)d_out;

  // workspace carve-up; H1h LAST (coop path needs the full 256 slots)
  char* p = (char*)d_ws;
  f16* A0 = (f16*)p;   p += (size_t)16384 * 512 * 2;    // x tokens, fp16
  f16* A1 = (f16*)p;   p += (size_t)16384 * 1024 * 2;   // h0 history
  f16* W0t = (f16*)p;  p += (size_t)4096 * 512 * 2;     // W0^T
  f16* U0t = (f16*)p;  p += (size_t)4096 * 1024 * 2;    // U0^T
  f16* W1t = (f16*)p;  p += (size_t)4096 * 1024 * 2;    // W1^T
  f16* U1t = (f16*)p;  p += (size_t)4096 * 1024 * 2;    // U1^T
  f16* XZ = (f16*)p;   p += (size_t)16384 * 4096 * 2;   // xz0, rows t*64+b
  float* C0 = (float*)p; p += 64 * 1024 * 4;            // cell L0 (fallback)
  float* C1 = (float*)p; p += 64 * 1024 * 4;            // cell L1 (fallback)
  unsigned* arr0 = (unsigned*)p; p += 256 * 32 * 4;     // L0 arrive lines
  unsigned* rel0 = (unsigned*)p; p += 256 * 32 * 4;     // L0 release lines
  unsigned* arr1 = (unsigned*)p; p += 256 * 32 * 4;     // L1 arrive lines
  unsigned* rel1 = (unsigned*)p; p += 256 * 32 * 4;     // L1 release lines
  unsigned* mir = (unsigned*)p; p += 256 * 32 * 4;      // epoch mirrors
  f16* H1h = (f16*)p;                                   // h1 history slots
  const size_t need_coop = (size_t)(p - (char*)d_ws) + (size_t)256 * 65536 * 2;

  // weight transposes + casts
  k_transpose_f16<<<512, 256, 0, stream>>>(W0, W0t, 512, 4096);
  k_transpose_f16<<<1024, 256, 0, stream>>>(U0, U0t, 1024, 4096);
  k_transpose_f16<<<1024, 256, 0, stream>>>(W1, W1t, 1024, 4096);
  k_transpose_f16<<<1024, 256, 0, stream>>>(U1, U1t, 1024, 4096);

  // embedding
  k_embed_f16<<<8192, 256, 0, stream>>>(tokens, emb, A0);

  // layer 0 input projection: xz0 = x @ W0 + b0
  k_gemm_f16<<<4096, 256, 0, stream>>>(A0, W0t, b0, XZ, 16384, 4096, 512);

  hipMemsetAsync(C0, 0, 64 * 1024 * 4 * 2, stream);   // C0+C1
  hipMemsetAsync(arr0, 0, 5 * 256 * 32 * 4, stream);  // all flag arrays

  bool coop_ok = (ws_size >= need_coop);
  if (coop_ok) {
    const f16* XZc = XZ; const f16* U0c = U0t; const f16* W1c = W1t;
    const f16* U1c = U1t; const float* b1c = b1;
    f16* A1p = A1; f16* H1p = H1h; float* outp = out;
    unsigned* a0 = arr0; unsigned* r0 = rel0;
    unsigned* a1 = arr1; unsigned* r1 = rel1; unsigned* mr = mir;
    void* kargs[] = {(void*)&XZc, (void*)&U0c, (void*)&W1c, (void*)&U1c,
                     (void*)&b1c, (void*)&A1p, (void*)&H1p, (void*)&outp,
                     (void*)&a0, (void*)&r0, (void*)&a1, (void*)&r1,
                     (void*)&mr};
    hipError_t e = hipLaunchCooperativeKernel((const void*)k_scan3, dim3(512),
                                              dim3(256), kargs, 0, stream);
    if (e != hipSuccess) {
      (void)hipGetLastError();
      coop_ok = false;
    }
  }
  if (!coop_ok) {
    for (int s = 0; s <= 256; ++s)
      k_step<<<256, 256, 0, stream>>>(XZ, U0t, W1t, U1t, b1, A1, H1h, C0, C1,
                                      out, s);
  }
}

// Round 9
// 3637.294 us; speedup vs baseline: 5.5552x; 1.0054x over previous
//
#include <hip/hip_runtime.h>

// LSTM encoder: V=32000 E=512 U=1024 L=2, B=64 T=256.
// Round 9: r8 decoupled scan + XCD-aware unit-group swizzle. blockIdx%8 maps
// to XCD; remapping block->units as i=(bid%8)*32+bid/8 gives XCD k the unit
// range [128k,128k+128), so each 128B line of XZ/out/A1 is consumed by ONE
// XCD (16 sharer blocks all L2-local). r8's FETCH_SIZE=949MB showed ~8x
// cross-XCD HBM amplification of XZ (3.7MB/step at 390GB/s ~= 9.5us/step =
// the measured floor). Also: xz prefetch issued AFTER the store-drain so the
// arrive flag doesn't wait on HBM read latency.

typedef _Float16 f16;
typedef _Float16 f16x8 __attribute__((ext_vector_type(8)));
typedef _Float16 f16x4 __attribute__((ext_vector_type(4)));
typedef float f32x4 __attribute__((ext_vector_type(4)));

__device__ __forceinline__ f32x4 mfma16x32(f16x8 a, f16x8 b, f32x4 c) {
  return __builtin_amdgcn_mfma_f32_16x16x32_f16(a, b, c, 0, 0, 0);
}

__device__ __forceinline__ void gl_lds16(const void* g, void* l) {
  __builtin_amdgcn_global_load_lds(
      (const __attribute__((address_space(1))) void*)g,
      (__attribute__((address_space(3))) void*)l, 16, 0, 0);
}

__device__ __forceinline__ float sigmoidf_(float x) {
  return 1.0f / (1.0f + expf(-x));
}

// write-through f16 store: lands at the L3 coherence point, no dirty L2 line
__device__ __forceinline__ void st_f16_sc(f16* p, float v) {
  f16 h = (f16)v;
  unsigned u = (unsigned)__builtin_bit_cast(unsigned short, h);
  asm volatile("global_store_short %0, %1, off sc0 sc1"
               :: "v"(p), "v"(u) : "memory");
}

__device__ __forceinline__ unsigned ld_flag(const unsigned* p) {
  return __hip_atomic_load(p, __ATOMIC_RELAXED, __HIP_MEMORY_SCOPE_AGENT);
}
__device__ __forceinline__ void st_flag(unsigned* p, unsigned v) {
  __hip_atomic_store(p, v, __ATOMIC_RELAXED, __HIP_MEMORY_SCOPE_AGENT);
}

// ---------- transpose + cast: D[n][k] = (f16)S[k][n] ----------
__global__ __launch_bounds__(256) void k_transpose_f16(
    const float* __restrict__ S, f16* __restrict__ D, int K, int N) {
  __shared__ float tile[64][65];
  int nk = K >> 6;
  int k0 = (blockIdx.x % nk) << 6;
  int n0 = (blockIdx.x / nk) << 6;
  int tc = threadIdx.x & 63;
  int tq = threadIdx.x >> 6;
#pragma unroll
  for (int r = 0; r < 16; ++r) {
    int kk = tq * 16 + r;
    tile[kk][tc] = S[(size_t)(k0 + kk) * N + (n0 + tc)];
  }
  __syncthreads();
#pragma unroll
  for (int r = 0; r < 16; ++r) {
    int nn = tq * 16 + r;
    D[(size_t)(n0 + nn) * K + (k0 + tc)] = (f16)tile[tc][nn];
  }
}

// ---------- embedding lookup -> fp16 A0[m][512], row m = t*64 + b ----------
__global__ __launch_bounds__(256) void k_embed_f16(
    const int* __restrict__ tok, const float* __restrict__ emb,
    f16* __restrict__ A0) {
  int i = blockIdx.x * 256 + threadIdx.x;
  int m = i >> 7;
  int e = (i & 127) << 2;
  int t = m >> 6, b = m & 63;
  int tk = tok[b * 256 + t];
  const float4 v = *(const float4*)(emb + (size_t)tk * 512 + e);
  f16x4 o = {(f16)v.x, (f16)v.y, (f16)v.z, (f16)v.w};
  *(f16x4*)(A0 + (size_t)m * 512 + e) = o;
}

// ---------- C[m][n] = (f16)(sum_k A[m][k]*Bt[n][k] + bias[n]) ----------
__global__ __launch_bounds__(256) void k_gemm_f16(
    const f16* __restrict__ A, const f16* __restrict__ Bt,
    const float* __restrict__ bias, f16* __restrict__ C,
    int M, int N, int K) {
  __shared__ f16 sA[2][128 * 32];
  __shared__ f16 sB[2][128 * 32];
  const int tid = threadIdx.x, lane = tid & 63, w = tid >> 6;
  const int mb = M >> 7;
  const int bm = blockIdx.x % mb, bn = blockIdx.x / mb;
  const int am0 = bm << 7, bn0 = bn << 7;
  const int wm = w >> 1, wn = w & 1;
  const int srow = lane >> 2, sch = lane & 3;

  f32x4 acc[4][4] = {};
  const int NT = K >> 5;
  int cur = 0;

  auto stage = [&](int kt, int buf) {
#pragma unroll
    for (int q2 = 0; q2 < 2; ++q2) {
      int q = w * 2 + q2;
      int row = q * 16 + srow;
      const f16* ga = A + (size_t)(am0 + row) * K + kt * 32 + sch * 8;
      const f16* gb = Bt + (size_t)(bn0 + row) * K + kt * 32 + sch * 8;
      gl_lds16(ga, (char*)&sA[buf][0] + q * 1024);
      gl_lds16(gb, (char*)&sB[buf][0] + q * 1024);
    }
  };

  stage(0, 0);
  __syncthreads();
  for (int kt = 0; kt < NT; ++kt) {
    if (kt + 1 < NT) stage(kt + 1, cur ^ 1);
    const f16* pa = &sA[cur][(wm * 64 + (lane & 15)) * 32 + (lane >> 4) * 8];
    const f16* pb = &sB[cur][(wn * 64 + (lane & 15)) * 32 + (lane >> 4) * 8];
    f16x8 av[4], bv[4];
#pragma unroll
    for (int mf = 0; mf < 4; ++mf) av[mf] = *(const f16x8*)(pa + mf * 512);
#pragma unroll
    for (int nf = 0; nf < 4; ++nf) bv[nf] = *(const f16x8*)(pb + nf * 512);
#pragma unroll
    for (int mf = 0; mf < 4; ++mf)
#pragma unroll
      for (int nf = 0; nf < 4; ++nf)
        acc[mf][nf] = mfma16x32(av[mf], bv[nf], acc[mf][nf]);
    __syncthreads();
    cur ^= 1;
  }

#pragma unroll
  for (int mf = 0; mf < 4; ++mf)
#pragma unroll
    for (int nf = 0; nf < 4; ++nf) {
      int col = bn0 + wn * 64 + nf * 16 + (lane & 15);
      float bs = bias[col];
#pragma unroll
      for (int r = 0; r < 4; ++r) {
        int row = am0 + wm * 64 + mf * 16 + (lane >> 4) * 4 + r;
        C[(size_t)row * N + col] = (f16)(acc[mf][nf][r] + bs);
      }
    }
}

// ---------- shared epilogue piece: 4-wave partial reduce through LDS ----------
__device__ __forceinline__ void reduce4(const f32x4 acc[4], float* zred,
                                        float z[4]) {
  const int tid = threadIdx.x, lane = tid & 63, w = tid >> 6;
  const int j = lane & 15, kg = lane >> 4;
#pragma unroll
  for (int mf = 0; mf < 4; ++mf)
#pragma unroll
    for (int r = 0; r < 4; ++r)
      zred[w * 1088 + (mf * 16 + kg * 4 + r) * 17 + j] = acc[mf][r];
  __syncthreads();
  const int erow = tid >> 2, euu = tid & 3;
#pragma unroll
  for (int g = 0; g < 4; ++g) {
#pragma unroll
    for (int wv = 0; wv < 4; ++wv)
      z[g] += zred[wv * 1088 + erow * 17 + g * 4 + euu];
  }
}

// ---------- decoupled persistent scan with XCD-local unit grouping ----------
// i = (rb%8)*32 + rb/8: XCD k (= bid%8) owns units [128k,128k+128) so every
// 128B line of XZ / out / A1-sliver is consumed within one XCD's L2.
__global__ __launch_bounds__(256, 2) void k_scan3(
    const f16* __restrict__ XZ, const f16* __restrict__ U0t,
    const f16* __restrict__ W1t, const f16* __restrict__ U1t,
    const float* __restrict__ b1, f16* __restrict__ A1,
    f16* __restrict__ H1h, float* __restrict__ out, unsigned* arr0,
    unsigned* rel0, unsigned* arr1, unsigned* rel1, unsigned* mir) {
  __shared__ float zred[4352];
  const int tid = threadIdx.x, lane = tid & 63, w = tid >> 6;
  const bool isL1 = (blockIdx.x >= 256);
  const int rb = isL1 ? (int)blockIdx.x - 256 : (int)blockIdx.x;
  const int i = ((rb & 7) << 5) + (rb >> 3);  // XCD-local unit-group swizzle
  const int u0 = i * 4;
  const int j = lane & 15, kg = lane >> 4;
  const int ncol = (j >> 2) * 1024 + u0 + (j & 3);
  const int woff = ncol * 1024 + w * 256 + kg * 8;
  const int aoff = j * 1024 + w * 256 + kg * 8;
  const int erow = tid >> 2, eu = u0 + (tid & 3);

  f16x8 bvA[8], bvB[8];
#pragma unroll
  for (int kt = 0; kt < 8; ++kt)
    bvA[kt] = *(const f16x8*)((isL1 ? W1t : U0t) + woff + kt * 32);
  if (isL1) {
#pragma unroll
    for (int kt = 0; kt < 8; ++kt)
      bvB[kt] = *(const f16x8*)(U1t + woff + kt * 32);
  }
  float c = 0.0f;

  if (!isL1) {
    // ================= layer 0 =================
    float xz[4];
#pragma unroll
    for (int g = 0; g < 4; ++g)
      xz[g] = (float)XZ[(size_t)erow * 4096 + g * 1024 + eu];

    for (int s = 0; s < 256; ++s) {
      f32x4 acc[4] = {};
      if (s > 0) {
        const f16* ap = A1 + (size_t)(s - 1) * 65536 + aoff;
#pragma unroll
        for (int kt = 0; kt < 8; ++kt)
#pragma unroll
          for (int mf = 0; mf < 4; ++mf)
            acc[mf] = mfma16x32(*(const f16x8*)(ap + mf * 16384 + kt * 32),
                                bvA[kt], acc[mf]);
      }
      float z[4] = {xz[0], xz[1], xz[2], xz[3]};
      reduce4(acc, zred, z);
      float gi = sigmoidf_(z[0]), gf = sigmoidf_(z[1]);
      float gg = tanhf(z[2]), go = sigmoidf_(z[3]);
      c = gf * c + gi * gg;
      st_f16_sc(&A1[(size_t)(s * 64 + erow) * 1024 + eu], go * tanhf(c));

      // drain the write-through store FIRST, then issue next-xz prefetch so
      // the arrive flag below never waits on read latency
      asm volatile("s_waitcnt vmcnt(0)" ::: "memory");
      float xzn[4] = {0.f, 0.f, 0.f, 0.f};
      if (s + 1 < 256) {
        const f16* xrow = XZ + (size_t)((s + 1) * 64 + erow) * 4096;
#pragma unroll
        for (int g = 0; g < 4; ++g) xzn[g] = (float)xrow[g * 1024 + eu];
      }
      __syncthreads();

      // barrier0(s): after it completes, epoch = s+1 (A1[0..s] visible)
      const unsigned v = (unsigned)s + 1u;
      if (i == 0) {
        if (tid > 0) {
          while (ld_flag(&arr0[(unsigned)tid * 32u]) < v)
            __builtin_amdgcn_s_sleep(1);
        }
        __syncthreads();  // all 255 arrivals observed
        if (tid > 0) st_flag(&rel0[(unsigned)tid * 32u], v);
        st_flag(&mir[(unsigned)tid * 32u], v);  // epoch to every L1 block
      } else {
        if (tid == 0) {
          st_flag(&arr0[(unsigned)i * 32u], v);
          while (ld_flag(&rel0[(unsigned)i * 32u]) < v)
            __builtin_amdgcn_s_sleep(1);
        }
        __syncthreads();
      }
#pragma unroll
      for (int g = 0; g < 4; ++g) xz[g] = xzn[g];
    }
  } else {
    // ================= layer 1 =================
    float bias1[4];
#pragma unroll
    for (int g = 0; g < 4; ++g) bias1[g] = b1[g * 1024 + eu];

    // prime: wait epoch 1, compute accW = W1 * h0(0)
    if (tid == 0) {
      while (ld_flag(&mir[(unsigned)i * 32u]) < 1u)
        __builtin_amdgcn_s_sleep(1);
    }
    __syncthreads();
    f32x4 accW[4] = {};
    {
      const f16* ap = A1 + aoff;
#pragma unroll
      for (int kt = 0; kt < 8; ++kt)
#pragma unroll
        for (int mf = 0; mf < 4; ++mf)
          accW[mf] = mfma16x32(*(const f16x8*)(ap + mf * 16384 + kt * 32),
                               bvA[kt], accW[mf]);
    }

    for (int t = 0; t < 256; ++t) {
      f32x4 acc[4] = {accW[0], accW[1], accW[2], accW[3]};
      if (t > 0) {
        const f16* hp = H1h + (size_t)(t - 1) * 65536 + aoff;
#pragma unroll
        for (int kt = 0; kt < 8; ++kt)
#pragma unroll
          for (int mf = 0; mf < 4; ++mf)
            acc[mf] = mfma16x32(*(const f16x8*)(hp + mf * 16384 + kt * 32),
                                bvB[kt], acc[mf]);
      }
      float z[4] = {bias1[0], bias1[1], bias1[2], bias1[3]};
      reduce4(acc, zred, z);
      float gi = sigmoidf_(z[0]), gf = sigmoidf_(z[1]);
      float gg = tanhf(z[2]), go = sigmoidf_(z[3]);
      c = gf * c + gi * gg;
      float hn = go * tanhf(c);
      out[(size_t)erow * 262144 + (size_t)t * 1024 + eu] = hn;
      if (t == 255) {
        out[16777216 + erow * 1024 + eu] = hn;
        out[16777216 + 65536 + erow * 1024 + eu] = c;
        break;  // last step: no publish/barrier needed
      }
      st_f16_sc(&H1h[(size_t)t * 65536 + erow * 1024 + eu], hn);

      // barrier1(t) with W1-pass overlap in the wait window
      asm volatile("s_waitcnt vmcnt(0)" ::: "memory");
      __syncthreads();
      const unsigned v = (unsigned)t + 1u;
      if (i == 0) {
        // leader: gather + release FIRST so workers aren't held up
        if (tid > 0) {
          while (ld_flag(&arr1[(unsigned)tid * 32u]) < v)
            __builtin_amdgcn_s_sleep(1);
        }
        __syncthreads();
        if (tid > 0) st_flag(&rel1[(unsigned)tid * 32u], v);
      } else {
        if (tid == 0) st_flag(&arr1[(unsigned)i * 32u], v);
      }
      // overlap: next step's W1 pass, gated on epoch t+2
      if (tid == 0) {
        while (ld_flag(&mir[(unsigned)i * 32u]) < v + 1u)
          __builtin_amdgcn_s_sleep(1);
      }
      __syncthreads();
      {
        const f16* ap = A1 + (size_t)(t + 1) * 65536 + aoff;
#pragma unroll
        for (int mf = 0; mf < 4; ++mf) acc[mf] = f32x4{0.f, 0.f, 0.f, 0.f};
#pragma unroll
        for (int kt = 0; kt < 8; ++kt)
#pragma unroll
          for (int mf = 0; mf < 4; ++mf)
            acc[mf] = mfma16x32(*(const f16x8*)(ap + mf * 16384 + kt * 32),
                                bvA[kt], acc[mf]);
#pragma unroll
        for (int mf = 0; mf < 4; ++mf) accW[mf] = acc[mf];
      }
      // wait for release (workers; leader already released)
      if (i != 0) {
        if (tid == 0) {
          while (ld_flag(&rel1[(unsigned)i * 32u]) < v)
            __builtin_amdgcn_s_sleep(1);
        }
        __syncthreads();
      }
    }
  }
}

// ---------- fallback: fused per-step kernel (proven r6/r7) ----------
__device__ __forceinline__ void step_once(
    int s, int u0, const f16x8 bvU0[8], const f16x8 bvW1[8],
    const f16x8 bvU1[8], const float bias1[4], const float xz[4],
    f16* __restrict__ A1, f16* __restrict__ H1h, int hmask,
    float& c0, float& c1, float* __restrict__ out, float* zred) {
  const int tid = threadIdx.x, lane = tid & 63, w = tid >> 6;
  const int j = lane & 15, kg = lane >> 4;
  const int aoff = j * 1024 + w * 256 + kg * 8;
  const int erow = tid >> 2;
  const int eu = u0 + (tid & 3);

  f32x4 accA[4] = {};
  f32x4 accB[4] = {};

  if (s >= 1) {
    const f16* ap = A1 + (size_t)(s - 1) * 65536 + aoff;
#pragma unroll
    for (int kt = 0; kt < 8; ++kt)
#pragma unroll
      for (int mf = 0; mf < 4; ++mf) {
        f16x8 av = *(const f16x8*)(ap + mf * 16384 + kt * 32);
        if (s < 256) accA[mf] = mfma16x32(av, bvU0[kt], accA[mf]);
        accB[mf] = mfma16x32(av, bvW1[kt], accB[mf]);
      }
    if (s >= 2) {
      const f16* hp = H1h + (size_t)((s - 2) & hmask) * 65536 + aoff;
#pragma unroll
      for (int kt = 0; kt < 8; ++kt)
#pragma unroll
        for (int mf = 0; mf < 4; ++mf)
          accB[mf] = mfma16x32(*(const f16x8*)(hp + mf * 16384 + kt * 32),
                               bvU1[kt], accB[mf]);
    }
  }

  if (s < 256) {
    float z[4] = {xz[0], xz[1], xz[2], xz[3]};
    reduce4(accA, zred, z);
    float gi = sigmoidf_(z[0]), gf = sigmoidf_(z[1]);
    float gg = tanhf(z[2]), go = sigmoidf_(z[3]);
    c0 = gf * c0 + gi * gg;
    st_f16_sc(&A1[(size_t)(s * 64 + erow) * 1024 + eu], go * tanhf(c0));
  }
  __syncthreads();

  if (s >= 1) {
    const int t = s - 1;
    float z[4] = {bias1[0], bias1[1], bias1[2], bias1[3]};
    reduce4(accB, zred, z);
    float gi = sigmoidf_(z[0]), gf = sigmoidf_(z[1]);
    float gg = tanhf(z[2]), go = sigmoidf_(z[3]);
    c1 = gf * c1 + gi * gg;
    float hn = go * tanhf(c1);
    st_f16_sc(&H1h[(size_t)(t & hmask) * 65536 + erow * 1024 + eu], hn);
    out[(size_t)erow * 262144 + (size_t)t * 1024 + eu] = hn;
    if (t == 255) {
      out[16777216 + erow * 1024 + eu] = hn;
      out[16777216 + 65536 + erow * 1024 + eu] = c1;
    }
  }
}

__global__ __launch_bounds__(256, 1) void k_step(
    const f16* __restrict__ XZ, const f16* __restrict__ U0t,
    const f16* __restrict__ W1t, const f16* __restrict__ U1t,
    const float* __restrict__ b1, f16* __restrict__ A1,
    f16* __restrict__ H1h, float* __restrict__ C0, float* __restrict__ C1,
    float* __restrict__ out, int s) {
  __shared__ float zred[4352];
  const int tid_ = threadIdx.x, lane_ = tid_ & 63, w_ = tid_ >> 6;
  const int bid_ = (int)blockIdx.x;
  const int i_ = ((bid_ & 7) << 5) + (bid_ >> 3);  // same XCD-local swizzle
  const int u0 = i_ * 4;
  const int j_ = lane_ & 15;
  const int kg_ = lane_ >> 4;
  const int ncol_ = (j_ >> 2) * 1024 + u0 + (j_ & 3);
  const int woff_ = ncol_ * 1024 + w_ * 256 + kg_ * 8;
  f16x8 bvU0[8], bvW1[8], bvU1[8];
#pragma unroll
  for (int kt = 0; kt < 8; ++kt) {
    bvU0[kt] = *(const f16x8*)(U0t + woff_ + kt * 32);
    bvW1[kt] = *(const f16x8*)(W1t + woff_ + kt * 32);
    bvU1[kt] = *(const f16x8*)(U1t + woff_ + kt * 32);
  }
  const int erow_ = tid_ >> 2;
  const int eu_ = u0 + (tid_ & 3);
  float bias1[4];
#pragma unroll
  for (int g = 0; g < 4; ++g) bias1[g] = b1[g * 1024 + eu_];

  float xz[4] = {0.f, 0.f, 0.f, 0.f};
  if (s < 256) {
    const f16* xrow = XZ + (size_t)(s * 64 + erow_) * 4096;
#pragma unroll
    for (int g = 0; g < 4; ++g) xz[g] = (float)xrow[g * 1024 + eu_];
  }
  float c0 = C0[erow_ * 1024 + eu_];
  float c1 = C1[erow_ * 1024 + eu_];
  step_once(s, u0, bvU0, bvW1, bvU1, bias1, xz, A1, H1h, 1, c0, c1, out,
            zred);
  C0[erow_ * 1024 + eu_] = c0;
  C1[erow_ * 1024 + eu_] = c1;
}

extern "C" void kernel_launch(void* const* d_in, const int* in_sizes, int n_in,
                              void* d_out, int out_size, void* d_ws, size_t ws_size,
                              hipStream_t stream) {
  (void)in_sizes; (void)n_in; (void)out_size;
  const int* tokens = (const int*)d_in[0];
  const float* emb = (const float*)d_in[1];
  const float* W0 = (const float*)d_in[2];
  const float* U0 = (const float*)d_in[3];
  const float* b0 = (const float*)d_in[4];
  const float* W1 = (const float*)d_in[5];
  const float* U1 = (const float*)d_in[6];
  const float* b1 = (const float*)d_in[7];
  float* out = (float*)d_out;

  // workspace carve-up; H1h LAST (coop path needs the full 256 slots)
  char* p = (char*)d_ws;
  f16* A0 = (f16*)p;   p += (size_t)16384 * 512 * 2;    // x tokens, fp16
  f16* A1 = (f16*)p;   p += (size_t)16384 * 1024 * 2;   // h0 history
  f16* W0t = (f16*)p;  p += (size_t)4096 * 512 * 2;     // W0^T
  f16* U0t = (f16*)p;  p += (size_t)4096 * 1024 * 2;    // U0^T
  f16* W1t = (f16*)p;  p += (size_t)4096 * 1024 * 2;    // W1^T
  f16* U1t = (f16*)p;  p += (size_t)4096 * 1024 * 2;    // U1^T
  f16* XZ = (f16*)p;   p += (size_t)16384 * 4096 * 2;   // xz0, rows t*64+b
  float* C0 = (float*)p; p += 64 * 1024 * 4;            // cell L0 (fallback)
  float* C1 = (float*)p; p += 64 * 1024 * 4;            // cell L1 (fallback)
  unsigned* arr0 = (unsigned*)p; p += 256 * 32 * 4;     // L0 arrive lines
  unsigned* rel0 = (unsigned*)p; p += 256 * 32 * 4;     // L0 release lines
  unsigned* arr1 = (unsigned*)p; p += 256 * 32 * 4;     // L1 arrive lines
  unsigned* rel1 = (unsigned*)p; p += 256 * 32 * 4;     // L1 release lines
  unsigned* mir = (unsigned*)p; p += 256 * 32 * 4;      // epoch mirrors
  f16* H1h = (f16*)p;                                   // h1 history slots
  const size_t need_coop = (size_t)(p - (char*)d_ws) + (size_t)256 * 65536 * 2;

  // weight transposes + casts
  k_transpose_f16<<<512, 256, 0, stream>>>(W0, W0t, 512, 4096);
  k_transpose_f16<<<1024, 256, 0, stream>>>(U0, U0t, 1024, 4096);
  k_transpose_f16<<<1024, 256, 0, stream>>>(W1, W1t, 1024, 4096);
  k_transpose_f16<<<1024, 256, 0, stream>>>(U1, U1t, 1024, 4096);

  // embedding
  k_embed_f16<<<8192, 256, 0, stream>>>(tokens, emb, A0);

  // layer 0 input projection: xz0 = x @ W0 + b0
  k_gemm_f16<<<4096, 256, 0, stream>>>(A0, W0t, b0, XZ, 16384, 4096, 512);

  hipMemsetAsync(C0, 0, 64 * 1024 * 4 * 2, stream);   // C0+C1
  hipMemsetAsync(arr0, 0, 5 * 256 * 32 * 4, stream);  // all flag arrays

  bool coop_ok = (ws_size >= need_coop);
  if (coop_ok) {
    const f16* XZc = XZ; const f16* U0c = U0t; const f16* W1c = W1t;
    const f16* U1c = U1t; const float* b1c = b1;
    f16* A1p = A1; f16* H1p = H1h; float* outp = out;
    unsigned* a0 = arr0; unsigned* r0 = rel0;
    unsigned* a1 = arr1; unsigned* r1 = rel1; unsigned* mr = mir;
    void* kargs[] = {(void*)&XZc, (void*)&U0c, (void*)&W1c, (void*)&U1c,
                     (void*)&b1c, (void*)&A1p, (void*)&H1p, (void*)&outp,
                     (void*)&a0, (void*)&r0, (void*)&a1, (void*)&r1,
                     (void*)&mr};
    hipError_t e = hipLaunchCooperativeKernel((const void*)k_scan3, dim3(512),
                                              dim3(256), kargs, 0, stream);
    if (e != hipSuccess) {
      (void)hipGetLastError();
      coop_ok = false;
    }
  }
  if (!coop_ok) {
    for (int s = 0; s <= 256; ++s)
      k_step<<<256, 256, 0, stream>>>(XZ, U0t, W1t, U1t, b1, A1, H1h, C0, C1,
                                      out, s);
  }
}

// Round 10
// 2433.952 us; speedup vs baseline: 8.3016x; 1.4944x over previous
//
#include <hip/hip_runtime.h>

// LSTM encoder: V=32000 E=512 U=1024 L=2, B=64 T=256.
// Round 10: halve the per-step h-broadcast. Each wave holds TWO 16-col
// weight sets (dual B-frags, 64 VGPR) so one A-fragment feeds two MFMAs;
// blocks split by batch-half (32 rows x 8 units). Per-XCD L2 volume/step:
// 12MB -> 6MB (~2.8 -> ~1.4us). Grid/barrier/occupancy identical to r9
// (512 blocks x 256 thr, 2/CU, fence-free write-through + flag barriers).

typedef _Float16 f16;
typedef _Float16 f16x8 __attribute__((ext_vector_type(8)));
typedef _Float16 f16x4 __attribute__((ext_vector_type(4)));
typedef float f32x4 __attribute__((ext_vector_type(4)));

__device__ __forceinline__ f32x4 mfma16x32(f16x8 a, f16x8 b, f32x4 c) {
  return __builtin_amdgcn_mfma_f32_16x16x32_f16(a, b, c, 0, 0, 0);
}

__device__ __forceinline__ void gl_lds16(const void* g, void* l) {
  __builtin_amdgcn_global_load_lds(
      (const __attribute__((address_space(1))) void*)g,
      (__attribute__((address_space(3))) void*)l, 16, 0, 0);
}

__device__ __forceinline__ float sigmoidf_(float x) {
  return 1.0f / (1.0f + expf(-x));
}

// write-through f16 store: lands at the L3 coherence point, no dirty L2 line
__device__ __forceinline__ void st_f16_sc(f16* p, float v) {
  f16 h = (f16)v;
  unsigned u = (unsigned)__builtin_bit_cast(unsigned short, h);
  asm volatile("global_store_short %0, %1, off sc0 sc1"
               :: "v"(p), "v"(u) : "memory");
}

__device__ __forceinline__ unsigned ld_flag(const unsigned* p) {
  return __hip_atomic_load(p, __ATOMIC_RELAXED, __HIP_MEMORY_SCOPE_AGENT);
}
__device__ __forceinline__ void st_flag(unsigned* p, unsigned v) {
  __hip_atomic_store(p, v, __ATOMIC_RELAXED, __HIP_MEMORY_SCOPE_AGENT);
}

// ---------- transpose + cast: D[n][k] = (f16)S[k][n] ----------
__global__ __launch_bounds__(256) void k_transpose_f16(
    const float* __restrict__ S, f16* __restrict__ D, int K, int N) {
  __shared__ float tile[64][65];
  int nk = K >> 6;
  int k0 = (blockIdx.x % nk) << 6;
  int n0 = (blockIdx.x / nk) << 6;
  int tc = threadIdx.x & 63;
  int tq = threadIdx.x >> 6;
#pragma unroll
  for (int r = 0; r < 16; ++r) {
    int kk = tq * 16 + r;
    tile[kk][tc] = S[(size_t)(k0 + kk) * N + (n0 + tc)];
  }
  __syncthreads();
#pragma unroll
  for (int r = 0; r < 16; ++r) {
    int nn = tq * 16 + r;
    D[(size_t)(n0 + nn) * K + (k0 + tc)] = (f16)tile[tc][nn];
  }
}

// ---------- embedding lookup -> fp16 A0[m][512], row m = t*64 + b ----------
__global__ __launch_bounds__(256) void k_embed_f16(
    const int* __restrict__ tok, const float* __restrict__ emb,
    f16* __restrict__ A0) {
  int i = blockIdx.x * 256 + threadIdx.x;
  int m = i >> 7;
  int e = (i & 127) << 2;
  int t = m >> 6, b = m & 63;
  int tk = tok[b * 256 + t];
  const float4 v = *(const float4*)(emb + (size_t)tk * 512 + e);
  f16x4 o = {(f16)v.x, (f16)v.y, (f16)v.z, (f16)v.w};
  *(f16x4*)(A0 + (size_t)m * 512 + e) = o;
}

// ---------- C[m][n] = (f16)(sum_k A[m][k]*Bt[n][k] + bias[n]) ----------
__global__ __launch_bounds__(256) void k_gemm_f16(
    const f16* __restrict__ A, const f16* __restrict__ Bt,
    const float* __restrict__ bias, f16* __restrict__ C,
    int M, int N, int K) {
  __shared__ f16 sA[2][128 * 32];
  __shared__ f16 sB[2][128 * 32];
  const int tid = threadIdx.x, lane = tid & 63, w = tid >> 6;
  const int mb = M >> 7;
  const int bm = blockIdx.x % mb, bn = blockIdx.x / mb;
  const int am0 = bm << 7, bn0 = bn << 7;
  const int wm = w >> 1, wn = w & 1;
  const int srow = lane >> 2, sch = lane & 3;

  f32x4 acc[4][4] = {};
  const int NT = K >> 5;
  int cur = 0;

  auto stage = [&](int kt, int buf) {
#pragma unroll
    for (int q2 = 0; q2 < 2; ++q2) {
      int q = w * 2 + q2;
      int row = q * 16 + srow;
      const f16* ga = A + (size_t)(am0 + row) * K + kt * 32 + sch * 8;
      const f16* gb = Bt + (size_t)(bn0 + row) * K + kt * 32 + sch * 8;
      gl_lds16(ga, (char*)&sA[buf][0] + q * 1024);
      gl_lds16(gb, (char*)&sB[buf][0] + q * 1024);
    }
  };

  stage(0, 0);
  __syncthreads();
  for (int kt = 0; kt < NT; ++kt) {
    if (kt + 1 < NT) stage(kt + 1, cur ^ 1);
    const f16* pa = &sA[cur][(wm * 64 + (lane & 15)) * 32 + (lane >> 4) * 8];
    const f16* pb = &sB[cur][(wn * 64 + (lane & 15)) * 32 + (lane >> 4) * 8];
    f16x8 av[4], bv[4];
#pragma unroll
    for (int mf = 0; mf < 4; ++mf) av[mf] = *(const f16x8*)(pa + mf * 512);
#pragma unroll
    for (int nf = 0; nf < 4; ++nf) bv[nf] = *(const f16x8*)(pb + nf * 512);
#pragma unroll
    for (int mf = 0; mf < 4; ++mf)
#pragma unroll
      for (int nf = 0; nf < 4; ++nf)
        acc[mf][nf] = mfma16x32(av[mf], bv[nf], acc[mf][nf]);
    __syncthreads();
    cur ^= 1;
  }

#pragma unroll
  for (int mf = 0; mf < 4; ++mf)
#pragma unroll
    for (int nf = 0; nf < 4; ++nf) {
      int col = bn0 + wn * 64 + nf * 16 + (lane & 15);
      float bs = bias[col];
#pragma unroll
      for (int r = 0; r < 4; ++r) {
        int row = am0 + wm * 64 + mf * 16 + (lane >> 4) * 4 + r;
        C[(size_t)row * N + col] = (f16)(acc[mf][nf][r] + bs);
      }
    }
}

// ---------- decoupled scan, dual-B-frag + batch-split blocks ----------
// 512 blocks x 256 thr. bid<256: L0; else L1. rb=0..255 per layer:
//   ug = (rb&7)*16 + (rb>>3)&15  (unit-group, 8 units; XCD-local)
//   rh = rb>>7                   (batch half: rows rh*32..rh*32+32)
// Wave w: K-chunk w*256; dual 16-col weight sets (units u0..u0+4 / +4..+8).
// Per block A-read: 32 rows x 1024 K = 64KB (L0) / 128KB (L1 two passes).
__global__ __launch_bounds__(256, 2) void k_scan4(
    const f16* __restrict__ XZ, const f16* __restrict__ U0t,
    const f16* __restrict__ W1t, const f16* __restrict__ U1t,
    const float* __restrict__ b1, f16* __restrict__ A1,
    f16* __restrict__ H1h, float* __restrict__ out, unsigned* arr0,
    unsigned* rel0, unsigned* arr1, unsigned* rel1, unsigned* mir) {
  __shared__ float zred[4352];  // [set q: 2176][wave: 544][row*17 + j]
  const int tid = threadIdx.x, lane = tid & 63, w = tid >> 6;
  const bool isL1 = (blockIdx.x >= 256);
  const int rb = isL1 ? (int)blockIdx.x - 256 : (int)blockIdx.x;
  const int ug = ((rb & 7) << 4) + ((rb >> 3) & 15);
  const int rh = rb >> 7;
  const int u0 = ug * 8;
  const int j = lane & 15, kg = lane >> 4;
  const int aoff = (rh * 32 + j) * 1024 + w * 256 + kg * 8;
  // epilogue: one (row, unit) per thread
  const int erl = tid >> 3;                   // local row 0..31
  const int eunit = tid & 7;
  const int q_e = eunit >> 2, euu = eunit & 3;
  const int erow = rh * 32 + erl;
  const int eu = u0 + eunit;

  // dual weight sets per wave
  const int wo0 = ((j >> 2) * 1024 + u0 + (j & 3)) * 1024 + w * 256 + kg * 8;
  const int wo1 = wo0 + 4 * 1024;
  f16x8 bA0[8], bA1[8], bB0[8], bB1[8];
  {
    const f16* base = isL1 ? W1t : U0t;
#pragma unroll
    for (int kt = 0; kt < 8; ++kt) {
      bA0[kt] = *(const f16x8*)(base + wo0 + kt * 32);
      bA1[kt] = *(const f16x8*)(base + wo1 + kt * 32);
    }
  }
  if (isL1) {
#pragma unroll
    for (int kt = 0; kt < 8; ++kt) {
      bB0[kt] = *(const f16x8*)(U1t + wo0 + kt * 32);
      bB1[kt] = *(const f16x8*)(U1t + wo1 + kt * 32);
    }
  }
  float c = 0.0f;  // this thread's (row,unit) cell state

  if (!isL1) {
    // ================= layer 0 =================
    float xz[4];
#pragma unroll
    for (int g = 0; g < 4; ++g)
      xz[g] = (float)XZ[(size_t)erow * 4096 + g * 1024 + eu];

    for (int s = 0; s < 256; ++s) {
      f32x4 a0[2] = {}, a1[2] = {};
      if (s > 0) {
        const f16* ap = A1 + (size_t)(s - 1) * 65536 + aoff;
#pragma unroll
        for (int kt = 0; kt < 8; ++kt)
#pragma unroll
          for (int mf = 0; mf < 2; ++mf) {
            f16x8 av = *(const f16x8*)(ap + mf * 16384 + kt * 32);
            a0[mf] = mfma16x32(av, bA0[kt], a0[mf]);
            a1[mf] = mfma16x32(av, bA1[kt], a1[mf]);
          }
      }
#pragma unroll
      for (int mf = 0; mf < 2; ++mf)
#pragma unroll
        for (int r = 0; r < 4; ++r) {
          zred[w * 544 + (mf * 16 + kg * 4 + r) * 17 + j] = a0[mf][r];
          zred[2176 + w * 544 + (mf * 16 + kg * 4 + r) * 17 + j] = a1[mf][r];
        }
      __syncthreads();
      float z[4];
#pragma unroll
      for (int g = 0; g < 4; ++g) {
        float sm = xz[g];
#pragma unroll
        for (int wv = 0; wv < 4; ++wv)
          sm += zred[q_e * 2176 + wv * 544 + erl * 17 + g * 4 + euu];
        z[g] = sm;
      }
      float gi = sigmoidf_(z[0]), gf = sigmoidf_(z[1]);
      float gg = tanhf(z[2]), go = sigmoidf_(z[3]);
      c = gf * c + gi * gg;
      st_f16_sc(&A1[(size_t)(s * 64 + erow) * 1024 + eu], go * tanhf(c));

      // drain stores, then prefetch next xz (completes under barrier wait)
      asm volatile("s_waitcnt vmcnt(0)" ::: "memory");
      float xzn[4] = {0.f, 0.f, 0.f, 0.f};
      if (s + 1 < 256) {
        const f16* xrow = XZ + (size_t)((s + 1) * 64 + erow) * 4096;
#pragma unroll
        for (int g = 0; g < 4; ++g) xzn[g] = (float)xrow[g * 1024 + eu];
      }
      __syncthreads();

      // barrier0(s); afterwards epoch = s+1 (A1[0..s] visible)
      const unsigned v = (unsigned)s + 1u;
      if (rb == 0) {
        if (tid > 0) {
          while (ld_flag(&arr0[(unsigned)tid * 32u]) < v)
            __builtin_amdgcn_s_sleep(1);
        }
        __syncthreads();  // all 255 arrivals observed
        if (tid > 0) st_flag(&rel0[(unsigned)tid * 32u], v);
        st_flag(&mir[(unsigned)tid * 32u], v);  // epoch to every L1 block
      } else {
        if (tid == 0) {
          st_flag(&arr0[(unsigned)rb * 32u], v);
          while (ld_flag(&rel0[(unsigned)rb * 32u]) < v)
            __builtin_amdgcn_s_sleep(1);
        }
        __syncthreads();
      }
#pragma unroll
      for (int g = 0; g < 4; ++g) xz[g] = xzn[g];
    }
  } else {
    // ================= layer 1 =================
    float bias1[4];
#pragma unroll
    for (int g = 0; g < 4; ++g) bias1[g] = b1[g * 1024 + eu];

    // prime: wait epoch 1, compute accW = W1 * h0(0)
    if (tid == 0) {
      while (ld_flag(&mir[(unsigned)rb * 32u]) < 1u)
        __builtin_amdgcn_s_sleep(1);
    }
    __syncthreads();
    f32x4 accW0[2] = {}, accW1[2] = {};
    {
      const f16* ap = A1 + aoff;
#pragma unroll
      for (int kt = 0; kt < 8; ++kt)
#pragma unroll
        for (int mf = 0; mf < 2; ++mf) {
          f16x8 av = *(const f16x8*)(ap + mf * 16384 + kt * 32);
          accW0[mf] = mfma16x32(av, bA0[kt], accW0[mf]);
          accW1[mf] = mfma16x32(av, bA1[kt], accW1[mf]);
        }
    }

    for (int t = 0; t < 256; ++t) {
      f32x4 a0[2] = {accW0[0], accW0[1]};
      f32x4 a1[2] = {accW1[0], accW1[1]};
      if (t > 0) {
        const f16* hp = H1h + (size_t)(t - 1) * 65536 + aoff;
#pragma unroll
        for (int kt = 0; kt < 8; ++kt)
#pragma unroll
          for (int mf = 0; mf < 2; ++mf) {
            f16x8 av = *(const f16x8*)(hp + mf * 16384 + kt * 32);
            a0[mf] = mfma16x32(av, bB0[kt], a0[mf]);
            a1[mf] = mfma16x32(av, bB1[kt], a1[mf]);
          }
      }
#pragma unroll
      for (int mf = 0; mf < 2; ++mf)
#pragma unroll
        for (int r = 0; r < 4; ++r) {
          zred[w * 544 + (mf * 16 + kg * 4 + r) * 17 + j] = a0[mf][r];
          zred[2176 + w * 544 + (mf * 16 + kg * 4 + r) * 17 + j] = a1[mf][r];
        }
      __syncthreads();
      float z[4];
#pragma unroll
      for (int g = 0; g < 4; ++g) {
        float sm = bias1[g];
#pragma unroll
        for (int wv = 0; wv < 4; ++wv)
          sm += zred[q_e * 2176 + wv * 544 + erl * 17 + g * 4 + euu];
        z[g] = sm;
      }
      float gi = sigmoidf_(z[0]), gf = sigmoidf_(z[1]);
      float gg = tanhf(z[2]), go = sigmoidf_(z[3]);
      c = gf * c + gi * gg;
      float hn = go * tanhf(c);
      out[(size_t)erow * 262144 + (size_t)t * 1024 + eu] = hn;
      if (t == 255) {
        out[16777216 + erow * 1024 + eu] = hn;
        out[16777216 + 65536 + erow * 1024 + eu] = c;
        break;  // last step: no publish/barrier needed
      }
      st_f16_sc(&H1h[(size_t)t * 65536 + erow * 1024 + eu], hn);

      // barrier1(t) with W1-pass overlap in the wait window
      asm volatile("s_waitcnt vmcnt(0)" ::: "memory");
      __syncthreads();
      const unsigned v = (unsigned)t + 1u;
      if (rb == 0) {
        // leader: gather + release FIRST so workers aren't held up
        if (tid > 0) {
          while (ld_flag(&arr1[(unsigned)tid * 32u]) < v)
            __builtin_amdgcn_s_sleep(1);
        }
        __syncthreads();
        if (tid > 0) st_flag(&rel1[(unsigned)tid * 32u], v);
      } else {
        if (tid == 0) st_flag(&arr1[(unsigned)rb * 32u], v);
      }
      // overlap: next step's W1 pass, gated on epoch t+2
      if (tid == 0) {
        while (ld_flag(&mir[(unsigned)rb * 32u]) < v + 1u)
          __builtin_amdgcn_s_sleep(1);
      }
      __syncthreads();
      {
        const f16* ap = A1 + (size_t)(t + 1) * 65536 + aoff;
        f32x4 t0[2] = {}, t1[2] = {};
#pragma unroll
        for (int kt = 0; kt < 8; ++kt)
#pragma unroll
          for (int mf = 0; mf < 2; ++mf) {
            f16x8 av = *(const f16x8*)(ap + mf * 16384 + kt * 32);
            t0[mf] = mfma16x32(av, bA0[kt], t0[mf]);
            t1[mf] = mfma16x32(av, bA1[kt], t1[mf]);
          }
#pragma unroll
        for (int mf = 0; mf < 2; ++mf) {
          accW0[mf] = t0[mf];
          accW1[mf] = t1[mf];
        }
      }
      // wait for release (workers; leader already released)
      if (rb != 0) {
        if (tid == 0) {
          while (ld_flag(&rel1[(unsigned)rb * 32u]) < v)
            __builtin_amdgcn_s_sleep(1);
        }
        __syncthreads();
      }
    }
  }
}

// ---------- fallback: fused per-step kernel (r9, proven) ----------
__device__ __forceinline__ void reduce4(const f32x4 acc[4], float* zred,
                                        float z[4]) {
  const int tid = threadIdx.x, lane = tid & 63, w = tid >> 6;
  const int j = lane & 15, kg = lane >> 4;
#pragma unroll
  for (int mf = 0; mf < 4; ++mf)
#pragma unroll
    for (int r = 0; r < 4; ++r)
      zred[w * 1088 + (mf * 16 + kg * 4 + r) * 17 + j] = acc[mf][r];
  __syncthreads();
  const int erow = tid >> 2, euu = tid & 3;
#pragma unroll
  for (int g = 0; g < 4; ++g) {
#pragma unroll
    for (int wv = 0; wv < 4; ++wv)
      z[g] += zred[wv * 1088 + erow * 17 + g * 4 + euu];
  }
}

__device__ __forceinline__ void step_once(
    int s, int u0, const f16x8 bvU0[8], const f16x8 bvW1[8],
    const f16x8 bvU1[8], const float bias1[4], const float xz[4],
    f16* __restrict__ A1, f16* __restrict__ H1h, int hmask,
    float& c0, float& c1, float* __restrict__ out, float* zred) {
  const int tid = threadIdx.x, lane = tid & 63, w = tid >> 6;
  const int j = lane & 15, kg = lane >> 4;
  const int aoff = j * 1024 + w * 256 + kg * 8;
  const int erow = tid >> 2;
  const int eu = u0 + (tid & 3);

  f32x4 accA[4] = {};
  f32x4 accB[4] = {};

  if (s >= 1) {
    const f16* ap = A1 + (size_t)(s - 1) * 65536 + aoff;
#pragma unroll
    for (int kt = 0; kt < 8; ++kt)
#pragma unroll
      for (int mf = 0; mf < 4; ++mf) {
        f16x8 av = *(const f16x8*)(ap + mf * 16384 + kt * 32);
        if (s < 256) accA[mf] = mfma16x32(av, bvU0[kt], accA[mf]);
        accB[mf] = mfma16x32(av, bvW1[kt], accB[mf]);
      }
    if (s >= 2) {
      const f16* hp = H1h + (size_t)((s - 2) & hmask) * 65536 + aoff;
#pragma unroll
      for (int kt = 0; kt < 8; ++kt)
#pragma unroll
        for (int mf = 0; mf < 4; ++mf)
          accB[mf] = mfma16x32(*(const f16x8*)(hp + mf * 16384 + kt * 32),
                               bvU1[kt], accB[mf]);
    }
  }

  if (s < 256) {
    float z[4] = {xz[0], xz[1], xz[2], xz[3]};
    reduce4(accA, zred, z);
    float gi = sigmoidf_(z[0]), gf = sigmoidf_(z[1]);
    float gg = tanhf(z[2]), go = sigmoidf_(z[3]);
    c0 = gf * c0 + gi * gg;
    st_f16_sc(&A1[(size_t)(s * 64 + erow) * 1024 + eu], go * tanhf(c0));
  }
  __syncthreads();

  if (s >= 1) {
    const int t = s - 1;
    float z[4] = {bias1[0], bias1[1], bias1[2], bias1[3]};
    reduce4(accB, zred, z);
    float gi = sigmoidf_(z[0]), gf = sigmoidf_(z[1]);
    float gg = tanhf(z[2]), go = sigmoidf_(z[3]);
    c1 = gf * c1 + gi * gg;
    float hn = go * tanhf(c1);
    st_f16_sc(&H1h[(size_t)(t & hmask) * 65536 + erow * 1024 + eu], hn);
    out[(size_t)erow * 262144 + (size_t)t * 1024 + eu] = hn;
    if (t == 255) {
      out[16777216 + erow * 1024 + eu] = hn;
      out[16777216 + 65536 + erow * 1024 + eu] = c1;
    }
  }
}

__global__ __launch_bounds__(256, 1) void k_step(
    const f16* __restrict__ XZ, const f16* __restrict__ U0t,
    const f16* __restrict__ W1t, const f16* __restrict__ U1t,
    const float* __restrict__ b1, f16* __restrict__ A1,
    f16* __restrict__ H1h, float* __restrict__ C0, float* __restrict__ C1,
    float* __restrict__ out, int s) {
  __shared__ float zred[4352];
  const int tid_ = threadIdx.x, lane_ = tid_ & 63, w_ = tid_ >> 6;
  const int bid_ = (int)blockIdx.x;
  const int i_ = ((bid_ & 7) << 5) + (bid_ >> 3);
  const int u0 = i_ * 4;
  const int j_ = lane_ & 15;
  const int kg_ = lane_ >> 4;
  const int ncol_ = (j_ >> 2) * 1024 + u0 + (j_ & 3);
  const int woff_ = ncol_ * 1024 + w_ * 256 + kg_ * 8;
  f16x8 bvU0[8], bvW1[8], bvU1[8];
#pragma unroll
  for (int kt = 0; kt < 8; ++kt) {
    bvU0[kt] = *(const f16x8*)(U0t + woff_ + kt * 32);
    bvW1[kt] = *(const f16x8*)(W1t + woff_ + kt * 32);
    bvU1[kt] = *(const f16x8*)(U1t + woff_ + kt * 32);
  }
  const int erow_ = tid_ >> 2;
  const int eu_ = u0 + (tid_ & 3);
  float bias1[4];
#pragma unroll
  for (int g = 0; g < 4; ++g) bias1[g] = b1[g * 1024 + eu_];

  float xz[4] = {0.f, 0.f, 0.f, 0.f};
  if (s < 256) {
    const f16* xrow = XZ + (size_t)(s * 64 + erow_) * 4096;
#pragma unroll
    for (int g = 0; g < 4; ++g) xz[g] = (float)xrow[g * 1024 + eu_];
  }
  float c0 = C0[erow_ * 1024 + eu_];
  float c1 = C1[erow_ * 1024 + eu_];
  step_once(s, u0, bvU0, bvW1, bvU1, bias1, xz, A1, H1h, 1, c0, c1, out,
            zred);
  C0[erow_ * 1024 + eu_] = c0;
  C1[erow_ * 1024 + eu_] = c1;
}

extern "C" void kernel_launch(void* const* d_in, const int* in_sizes, int n_in,
                              void* d_out, int out_size, void* d_ws, size_t ws_size,
                              hipStream_t stream) {
  (void)in_sizes; (void)n_in; (void)out_size;
  const int* tokens = (const int*)d_in[0];
  const float* emb = (const float*)d_in[1];
  const float* W0 = (const float*)d_in[2];
  const float* U0 = (const float*)d_in[3];
  const float* b0 = (const float*)d_in[4];
  const float* W1 = (const float*)d_in[5];
  const float* U1 = (const float*)d_in[6];
  const float* b1 = (const float*)d_in[7];
  float* out = (float*)d_out;

  // workspace carve-up; H1h LAST (coop path needs the full 256 slots)
  char* p = (char*)d_ws;
  f16* A0 = (f16*)p;   p += (size_t)16384 * 512 * 2;    // x tokens, fp16
  f16* A1 = (f16*)p;   p += (size_t)16384 * 1024 * 2;   // h0 history
  f16* W0t = (f16*)p;  p += (size_t)4096 * 512 * 2;     // W0^T
  f16* U0t = (f16*)p;  p += (size_t)4096 * 1024 * 2;    // U0^T
  f16* W1t = (f16*)p;  p += (size_t)4096 * 1024 * 2;    // W1^T
  f16* U1t = (f16*)p;  p += (size_t)4096 * 1024 * 2;    // U1^T
  f16* XZ = (f16*)p;   p += (size_t)16384 * 4096 * 2;   // xz0, rows t*64+b
  float* C0 = (float*)p; p += 64 * 1024 * 4;            // cell L0 (fallback)
  float* C1 = (float*)p; p += 64 * 1024 * 4;            // cell L1 (fallback)
  unsigned* arr0 = (unsigned*)p; p += 256 * 32 * 4;     // L0 arrive lines
  unsigned* rel0 = (unsigned*)p; p += 256 * 32 * 4;     // L0 release lines
  unsigned* arr1 = (unsigned*)p; p += 256 * 32 * 4;     // L1 arrive lines
  unsigned* rel1 = (unsigned*)p; p += 256 * 32 * 4;     // L1 release lines
  unsigned* mir = (unsigned*)p; p += 256 * 32 * 4;      // epoch mirrors
  f16* H1h = (f16*)p;                                   // h1 history slots
  const size_t need_coop = (size_t)(p - (char*)d_ws) + (size_t)256 * 65536 * 2;

  // weight transposes + casts
  k_transpose_f16<<<512, 256, 0, stream>>>(W0, W0t, 512, 4096);
  k_transpose_f16<<<1024, 256, 0, stream>>>(U0, U0t, 1024, 4096);
  k_transpose_f16<<<1024, 256, 0, stream>>>(W1, W1t, 1024, 4096);
  k_transpose_f16<<<1024, 256, 0, stream>>>(U1, U1t, 1024, 4096);

  // embedding
  k_embed_f16<<<8192, 256, 0, stream>>>(tokens, emb, A0);

  // layer 0 input projection: xz0 = x @ W0 + b0
  k_gemm_f16<<<4096, 256, 0, stream>>>(A0, W0t, b0, XZ, 16384, 4096, 512);

  hipMemsetAsync(C0, 0, 64 * 1024 * 4 * 2, stream);   // C0+C1
  hipMemsetAsync(arr0, 0, 5 * 256 * 32 * 4, stream);  // all flag arrays

  bool coop_ok = (ws_size >= need_coop);
  if (coop_ok) {
    const f16* XZc = XZ; const f16* U0c = U0t; const f16* W1c = W1t;
    const f16* U1c = U1t; const float* b1c = b1;
    f16* A1p = A1; f16* H1p = H1h; float* outp = out;
    unsigned* a0 = arr0; unsigned* r0 = rel0;
    unsigned* a1 = arr1; unsigned* r1 = rel1; unsigned* mr = mir;
    void* kargs[] = {(void*)&XZc, (void*)&U0c, (void*)&W1c, (void*)&U1c,
                     (void*)&b1c, (void*)&A1p, (void*)&H1p, (void*)&outp,
                     (void*)&a0, (void*)&r0, (void*)&a1, (void*)&r1,
                     (void*)&mr};
    hipError_t e = hipLaunchCooperativeKernel((const void*)k_scan4, dim3(512),
                                              dim3(256), kargs, 0, stream);
    if (e != hipSuccess) {
      (void)hipGetLastError();
      coop_ok = false;
    }
  }
  if (!coop_ok) {
    for (int s = 0; s <= 256; ++s)
      k_step<<<256, 256, 0, stream>>>(XZ, U0t, W1t, U1t, b1, A1, H1h, C0, C1,
                                      out, s);
  }
}